// Round 1
// baseline (2070.818 us; speedup 1.0000x reference)
//
#include <hip/hip_runtime.h>
#include <hip/hip_bf16.h>
#include <math.h>

// ---------------------------------------------------------------------------
// GNN: lin(128->32) -> 3x GATConv(heads=1, self-loops) -> edge MLP
// Baseline strategy: atomics for segment max/sum/scatter; factorized edge MLP.
// ---------------------------------------------------------------------------

// Tiled GEMM: out[n x M] = in[n x K] @ W[K x M] (+bias) (+relu)
// Optionally computes per-node alpha_src = h . avec_s, alpha_dst = h . avec_d.
template<int K, int M, bool RELU, bool ALPHA>
__global__ __launch_bounds__(256) void gemm_kernel(
    const float* __restrict__ in, const float* __restrict__ W,
    const float* __restrict__ bias, float* __restrict__ out,
    const float* __restrict__ avec_s, const float* __restrict__ avec_d,
    float* __restrict__ alpha_s, float* __restrict__ alpha_d, int n)
{
    __shared__ float sW[K][M];
    __shared__ float sX[64][K + 1];   // +1 pad: kill 32-way bank conflict

    for (int i = threadIdx.x; i < K * M; i += 256)
        sW[i / M][i % M] = W[i];

    const int base = blockIdx.x * 64;
    for (int i = threadIdx.x; i < 64 * K; i += 256) {
        int r = i / K, c = i % K;
        int node = base + r;
        sX[r][c] = (node < n) ? in[(size_t)node * K + c] : 0.f;
    }
    __syncthreads();

    const int r  = threadIdx.x & 63;
    const int cg = threadIdx.x >> 6;       // 0..3
    constexpr int CPT = M / 4;             // cols per thread
    const int c0 = cg * CPT;

    float acc[CPT];
    #pragma unroll
    for (int j = 0; j < CPT; ++j) acc[j] = 0.f;

    #pragma unroll 4
    for (int k = 0; k < K; ++k) {
        float xv = sX[r][k];
        #pragma unroll
        for (int j = 0; j < CPT; ++j) acc[j] = fmaf(xv, sW[k][c0 + j], acc[j]);
    }

    const int node = base + r;
    if (node < n) {
        #pragma unroll
        for (int j = 0; j < CPT; ++j) {
            float v = acc[j] + (bias ? bias[c0 + j] : 0.f);
            if (RELU) v = fmaxf(v, 0.f);
            acc[j] = v;
            out[(size_t)node * M + c0 + j] = v;
        }
    }

    if constexpr (ALPHA) {
        __shared__ float sAS[4][64];
        __shared__ float sAD[4][64];
        float ps = 0.f, pd = 0.f;
        #pragma unroll
        for (int j = 0; j < CPT; ++j) {
            ps = fmaf(acc[j], avec_s[c0 + j], ps);
            pd = fmaf(acc[j], avec_d[c0 + j], pd);
        }
        sAS[cg][r] = ps;
        sAD[cg][r] = pd;
        __syncthreads();
        if (threadIdx.x < 64 && node < n) {
            alpha_s[node] = sAS[0][r] + sAS[1][r] + sAS[2][r] + sAS[3][r];
            alpha_d[node] = sAD[0][r] + sAD[1][r] + sAD[2][r] + sAD[3][r];
        }
    }
}

// Init per-layer state: accum=0, den=0, amax=enc(-inf)
__global__ void gat_init(unsigned* __restrict__ amaxu, float* __restrict__ den,
                         float* __restrict__ accum, int n)
{
    int i = blockIdx.x * 256 + threadIdx.x;
    if (i < n * 64) accum[i] = 0.f;
    if (i < n) { amaxu[i] = 0x007FFFFFu; den[i] = 0.f; }
}

__device__ __forceinline__ unsigned enc_f32(float f) {
    unsigned u = __float_as_uint(f);
    return (u & 0x80000000u) ? ~u : (u | 0x80000000u);
}
__device__ __forceinline__ float dec_f32(unsigned u) {
    return __uint_as_float((u & 0x80000000u) ? (u & 0x7FFFFFFFu) : ~u);
}

// Pass 1: per-edge logit + leaky_relu, atomic segment max over dst
__global__ __launch_bounds__(256) void gat_max(
    const int* __restrict__ ei, const float* __restrict__ as_,
    const float* __restrict__ ad_, float* __restrict__ logit,
    unsigned* __restrict__ amaxu, int E, int n)
{
    int e = blockIdx.x * 256 + threadIdx.x;
    int total = E + n;
    if (e >= total) return;
    int s, d;
    if (e < E) { s = ei[e]; d = ei[E + e]; }
    else       { s = d = e - E; }
    float lg = as_[s] + ad_[d];
    lg = (lg >= 0.f) ? lg : 0.2f * lg;
    logit[e] = lg;
    atomicMax(amaxu + d, enc_f32(lg));
}

// Pass 2: ex = exp(logit - amax[d]); den[d] += ex; accum[d] += h[s]*ex
// 16 lanes cooperate per edge (4 cols each, coalesced 64B atomic bursts).
__global__ __launch_bounds__(256) void gat_scatter(
    const int* __restrict__ ei, const float* __restrict__ h,
    const float* __restrict__ logit, const unsigned* __restrict__ amaxu,
    float* __restrict__ den, float* __restrict__ accum, int E, int n)
{
    int tid = blockIdx.x * 256 + threadIdx.x;
    int e = tid >> 4;
    int l = tid & 15;
    int total = E + n;
    if (e >= total) return;
    int s, d;
    if (e < E) { s = ei[e]; d = ei[E + e]; }
    else       { s = d = e - E; }
    float amax = dec_f32(amaxu[d]);
    float ex = __expf(logit[e] - amax);
    if (l == 0) atomicAdd(den + d, ex);
    const float* hs = h + (size_t)s * 64;
    float* ac = accum + (size_t)d * 64;
    #pragma unroll
    for (int k = 0; k < 4; ++k) {
        int c = l + 16 * k;
        atomicAdd(ac + c, hs[c] * ex);
    }
}

// Pass 3: out = accum/(den+eps) + bias (+relu), per (node,col)
template<bool RELU>
__global__ void gat_norm(const float* __restrict__ accum,
                         const float* __restrict__ den,
                         const float* __restrict__ bias,
                         float* __restrict__ out, int n)
{
    int i = blockIdx.x * 256 + threadIdx.x;
    if (i >= n * 64) return;
    int node = i >> 6, c = i & 63;
    float v = accum[i] / (den[node] + 1e-16f) + bias[c];
    if (RELU) v = fmaxf(v, 0.f);
    out[i] = v;
}

// Final edge MLP: out[e] = relu(Ps[s] + Pd[d]) . Wm2 + bm2, 32 lanes/edge
__global__ __launch_bounds__(256) void edge_mlp(
    const int* __restrict__ ei, const float* __restrict__ ps,
    const float* __restrict__ pd, const float* __restrict__ Wm2,
    const float* __restrict__ bm2, float* __restrict__ out, int E)
{
    int tid = blockIdx.x * 256 + threadIdx.x;
    int e = tid >> 5;
    int l = tid & 31;
    if (e >= E) return;
    int s = ei[e], d = ei[E + e];
    float v = ps[(size_t)s * 32 + l] + pd[(size_t)d * 32 + l];
    v = fmaxf(v, 0.f);
    float p = v * Wm2[l];
    p += __shfl_down(p, 16, 32);
    p += __shfl_down(p, 8, 32);
    p += __shfl_down(p, 4, 32);
    p += __shfl_down(p, 2, 32);
    p += __shfl_down(p, 1, 32);
    if (l == 0) out[e] = p + bm2[0];
}

extern "C" void kernel_launch(void* const* d_in, const int* in_sizes, int n_in,
                              void* d_out, int out_size, void* d_ws, size_t ws_size,
                              hipStream_t stream)
{
    const float* x   = (const float*)d_in[0];
    const int*   ei  = (const int*)d_in[1];
    const float* W0  = (const float*)d_in[2];
    const float* b0  = (const float*)d_in[3];
    const float* W1  = (const float*)d_in[4];
    const float* as1 = (const float*)d_in[5];
    const float* ad1 = (const float*)d_in[6];
    const float* b1  = (const float*)d_in[7];
    const float* W2  = (const float*)d_in[8];
    const float* as2 = (const float*)d_in[9];
    const float* ad2 = (const float*)d_in[10];
    const float* b2  = (const float*)d_in[11];
    const float* W3  = (const float*)d_in[12];
    const float* as3 = (const float*)d_in[13];
    const float* ad3 = (const float*)d_in[14];
    const float* b3  = (const float*)d_in[15];
    const float* Wm1 = (const float*)d_in[16];
    const float* bm1 = (const float*)d_in[17];
    const float* Wm2 = (const float*)d_in[18];
    const float* bm2 = (const float*)d_in[19];
    float* out = (float*)d_out;

    const int N = in_sizes[0] / 128;
    const int E = in_sizes[1] / 2;
    const int Etot = E + N;

    // Workspace layout (floats)
    float* ws = (float*)d_ws;
    float* A       = ws;                       // N x 64
    float* B       = A + (size_t)N * 64;       // N x 64
    float* C       = B + (size_t)N * 64;       // N x 64
    float* alpha_s = C + (size_t)N * 64;       // N
    float* alpha_d = alpha_s + N;              // N
    unsigned* amaxu = (unsigned*)(alpha_d + N);// N
    float* den     = (float*)(amaxu + N);      // N
    float* logit   = den + N;                  // E + N

    const int gNode64 = (N + 63) / 64;
    const int gN64    = (N * 64 + 255) / 256;
    const int gEdge   = (Etot + 255) / 256;
    const int gScat   = (Etot * 16 + 255) / 256;
    const int gMlp    = (E * 32 + 255) / 256;

    // h0 = x @ W0 + b0  -> A (N x 32)
    gemm_kernel<128, 32, false, false><<<gNode64, 256, 0, stream>>>(
        x, W0, b0, A, nullptr, nullptr, nullptr, nullptr, N);

    // ---- GAT layer 1: in A(32) -> h B(64) -> out C ----
    gemm_kernel<32, 64, false, true><<<gNode64, 256, 0, stream>>>(
        A, W1, nullptr, B, as1, ad1, alpha_s, alpha_d, N);
    gat_init<<<gN64, 256, 0, stream>>>(amaxu, den, C, N);
    gat_max<<<gEdge, 256, 0, stream>>>(ei, alpha_s, alpha_d, logit, amaxu, E, N);
    gat_scatter<<<gScat, 256, 0, stream>>>(ei, B, logit, amaxu, den, C, E, N);
    gat_norm<true><<<gN64, 256, 0, stream>>>(C, den, b1, C, N);

    // ---- GAT layer 2: in C -> h B -> out A ----
    gemm_kernel<64, 64, false, true><<<gNode64, 256, 0, stream>>>(
        C, W2, nullptr, B, as2, ad2, alpha_s, alpha_d, N);
    gat_init<<<gN64, 256, 0, stream>>>(amaxu, den, A, N);
    gat_max<<<gEdge, 256, 0, stream>>>(ei, alpha_s, alpha_d, logit, amaxu, E, N);
    gat_scatter<<<gScat, 256, 0, stream>>>(ei, B, logit, amaxu, den, A, E, N);
    gat_norm<true><<<gN64, 256, 0, stream>>>(A, den, b2, A, N);

    // ---- GAT layer 3: in A -> h B -> out C (no relu) ----
    gemm_kernel<64, 64, false, true><<<gNode64, 256, 0, stream>>>(
        A, W3, nullptr, B, as3, ad3, alpha_s, alpha_d, N);
    gat_init<<<gN64, 256, 0, stream>>>(amaxu, den, C, N);
    gat_max<<<gEdge, 256, 0, stream>>>(ei, alpha_s, alpha_d, logit, amaxu, E, N);
    gat_scatter<<<gScat, 256, 0, stream>>>(ei, B, logit, amaxu, den, C, E, N);
    gat_norm<false><<<gN64, 256, 0, stream>>>(C, den, b3, C, N);

    // ---- Final MLP, factorized over nodes ----
    // P_src = h3 @ Wm1[0:64]  + bm1 -> A[0 : 32N]
    // P_dst = h3 @ Wm1[64:128]      -> A[32N : 64N]
    float* Psrc = A;
    float* Pdst = A + (size_t)N * 32;
    gemm_kernel<64, 32, false, false><<<gNode64, 256, 0, stream>>>(
        C, Wm1, bm1, Psrc, nullptr, nullptr, nullptr, nullptr, N);
    gemm_kernel<64, 32, false, false><<<gNode64, 256, 0, stream>>>(
        C, Wm1 + 64 * 32, nullptr, Pdst, nullptr, nullptr, nullptr, nullptr, N);

    edge_mlp<<<gMlp, 256, 0, stream>>>(ei, Psrc, Pdst, Wm2, bm2, out, E);
}

// Round 3
// 1119.424 us; speedup vs baseline: 1.8499x; 1.8499x over previous
//
#include <hip/hip_runtime.h>
#include <hip/hip_bf16.h>
#include <math.h>

// ---------------------------------------------------------------------------
// GNN: lin(128->32) -> 3x GATConv(heads=1, self-loops) -> edge MLP
// R1: CSR-by-dst built once; per-layer fused gather (no atomics in hot path).
// R2: identical resubmit (R1 bench was GPUAcquisitionTimeout — no data).
// ---------------------------------------------------------------------------

// Tiled GEMM: out[n x M] = in[n x K] @ W[K x M] (+bias) (+relu)
// Optionally computes per-node alpha_src = h . avec_s, alpha_dst = h . avec_d.
template<int K, int M, bool RELU, bool ALPHA>
__global__ __launch_bounds__(256) void gemm_kernel(
    const float* __restrict__ in, const float* __restrict__ W,
    const float* __restrict__ bias, float* __restrict__ out,
    const float* __restrict__ avec_s, const float* __restrict__ avec_d,
    float* __restrict__ alpha_s, float* __restrict__ alpha_d, int n)
{
    __shared__ float sW[K][M];
    __shared__ float sX[64][K + 1];   // +1 pad: kill bank conflicts

    for (int i = threadIdx.x; i < K * M; i += 256)
        sW[i / M][i % M] = W[i];

    const int base = blockIdx.x * 64;
    for (int i = threadIdx.x; i < 64 * K; i += 256) {
        int r = i / K, c = i % K;
        int node = base + r;
        sX[r][c] = (node < n) ? in[(size_t)node * K + c] : 0.f;
    }
    __syncthreads();

    const int r  = threadIdx.x & 63;
    const int cg = threadIdx.x >> 6;       // 0..3
    constexpr int CPT = M / 4;             // cols per thread
    const int c0 = cg * CPT;

    float acc[CPT];
    #pragma unroll
    for (int j = 0; j < CPT; ++j) acc[j] = 0.f;

    #pragma unroll 4
    for (int k = 0; k < K; ++k) {
        float xv = sX[r][k];
        #pragma unroll
        for (int j = 0; j < CPT; ++j) acc[j] = fmaf(xv, sW[k][c0 + j], acc[j]);
    }

    const int node = base + r;
    if (node < n) {
        #pragma unroll
        for (int j = 0; j < CPT; ++j) {
            float v = acc[j] + (bias ? bias[c0 + j] : 0.f);
            if (RELU) v = fmaxf(v, 0.f);
            acc[j] = v;
            out[(size_t)node * M + c0 + j] = v;
        }
    }

    if constexpr (ALPHA) {
        __shared__ float sAS[4][64];
        __shared__ float sAD[4][64];
        float ps = 0.f, pd = 0.f;
        #pragma unroll
        for (int j = 0; j < CPT; ++j) {
            ps = fmaf(acc[j], avec_s[c0 + j], ps);
            pd = fmaf(acc[j], avec_d[c0 + j], pd);
        }
        sAS[cg][r] = ps;
        sAD[cg][r] = pd;
        __syncthreads();
        if (threadIdx.x < 64 && node < n) {
            alpha_s[node] = sAS[0][r] + sAS[1][r] + sAS[2][r] + sAS[3][r];
            alpha_d[node] = sAD[0][r] + sAD[1][r] + sAD[2][r] + sAD[3][r];
        }
    }
}

// ---- CSR build (once per launch; edge set shared by all 3 GAT layers) ----

// counts[i] = 1 (self loop)
__global__ void csr_init(int* __restrict__ counts, int n) {
    int i = blockIdx.x * 256 + threadIdx.x;
    if (i < n) counts[i] = 1;
}

__global__ void csr_count(const int* __restrict__ ei, int* __restrict__ counts, int E) {
    int i = blockIdx.x * 256 + threadIdx.x;
    if (i < E) atomicAdd(counts + ei[E + i], 1);
}

// Single-block exclusive scan of counts -> row_ptr (and cursor copy).
__global__ __launch_bounds__(1024) void csr_scan(
    const int* __restrict__ counts, int* __restrict__ row_ptr,
    int* __restrict__ cursor, int n)
{
    __shared__ int part[1024];
    const int t = threadIdx.x;
    const int chunk = (n + 1023) >> 10;
    const int lo = t * chunk;
    const int hi = min(lo + chunk, n);
    int s = 0;
    for (int i = lo; i < hi; ++i) s += counts[i];
    part[t] = s;
    __syncthreads();
    for (int off = 1; off < 1024; off <<= 1) {
        int v = (t >= off) ? part[t - off] : 0;
        __syncthreads();
        part[t] += v;
        __syncthreads();
    }
    int off = (t == 0) ? 0 : part[t - 1];
    for (int i = lo; i < hi; ++i) {
        row_ptr[i] = off;
        cursor[i] = off;
        off += counts[i];
    }
    if (t == 0) row_ptr[n] = part[1023];
}

// Scatter src ids into CSR order (edges then self-loops).
__global__ void csr_fill(const int* __restrict__ ei, int* __restrict__ cursor,
                         int* __restrict__ cols, int E, int n)
{
    int i = blockIdx.x * 256 + threadIdx.x;
    int total = E + n;
    if (i >= total) return;
    int s, d;
    if (i < E) { s = ei[i]; d = ei[E + i]; }
    else       { s = d = i - E; }
    int pos = atomicAdd(cursor + d, 1);
    cols[pos] = s;
}

// ---- Fused GAT aggregation: max + softmax + weighted gather + bias(+relu) ----
// 16 lanes per dst node, 4 cols each (float4).
template<bool RELU>
__global__ __launch_bounds__(256) void gat_gather(
    const int* __restrict__ row_ptr, const int* __restrict__ cols,
    const float* __restrict__ h, const float* __restrict__ as_,
    const float* __restrict__ ad_, const float* __restrict__ bias,
    float* __restrict__ out, int n)
{
    const int g = blockIdx.x * 16 + (threadIdx.x >> 4);   // dst node
    const int l = threadIdx.x & 15;
    if (g >= n) return;
    const int rp0 = row_ptr[g], rp1 = row_ptr[g + 1];
    const float adv = ad_[g];

    // pass 1: segment max (lane-parallel over edges)
    float amax = -1e30f;
    for (int i = rp0 + l; i < rp1; i += 16) {
        float lg = as_[cols[i]] + adv;
        lg = (lg >= 0.f) ? lg : 0.2f * lg;
        amax = fmaxf(amax, lg);
    }
    amax = fmaxf(amax, __shfl_xor(amax, 1));
    amax = fmaxf(amax, __shfl_xor(amax, 2));
    amax = fmaxf(amax, __shfl_xor(amax, 4));
    amax = fmaxf(amax, __shfl_xor(amax, 8));

    // pass 2: exp-weighted accumulate (serial over edges, coalesced h loads)
    float den = 0.f;
    float4 acc = make_float4(0.f, 0.f, 0.f, 0.f);
    for (int i = rp0; i < rp1; ++i) {
        int c = cols[i];                    // same addr across group: broadcast
        float lg = as_[c] + adv;
        lg = (lg >= 0.f) ? lg : 0.2f * lg;
        float ex = __expf(lg - amax);
        den += ex;
        float4 hv = *(const float4*)(h + (size_t)c * 64 + l * 4);
        acc.x = fmaf(ex, hv.x, acc.x);
        acc.y = fmaf(ex, hv.y, acc.y);
        acc.z = fmaf(ex, hv.z, acc.z);
        acc.w = fmaf(ex, hv.w, acc.w);
    }
    float inv = 1.f / (den + 1e-16f);
    float4 o;
    o.x = acc.x * inv + bias[l * 4 + 0];
    o.y = acc.y * inv + bias[l * 4 + 1];
    o.z = acc.z * inv + bias[l * 4 + 2];
    o.w = acc.w * inv + bias[l * 4 + 3];
    if (RELU) {
        o.x = fmaxf(o.x, 0.f); o.y = fmaxf(o.y, 0.f);
        o.z = fmaxf(o.z, 0.f); o.w = fmaxf(o.w, 0.f);
    }
    *(float4*)(out + (size_t)g * 64 + l * 4) = o;
}

// Final edge MLP: out[e] = relu(Ps[s] + Pd[d]) . Wm2 + bm2, 8 lanes/edge.
__global__ __launch_bounds__(256) void edge_mlp(
    const int* __restrict__ ei, const float* __restrict__ ps,
    const float* __restrict__ pd, const float* __restrict__ Wm2,
    const float* __restrict__ bm2, float* __restrict__ out, int E)
{
    int tid = blockIdx.x * 256 + threadIdx.x;
    int e = tid >> 3;
    int l = tid & 7;
    if (e >= E) return;
    int s = ei[e], d = ei[E + e];
    float4 a = *(const float4*)(ps + (size_t)s * 32 + l * 4);
    float4 b = *(const float4*)(pd + (size_t)d * 32 + l * 4);
    float4 w = *(const float4*)(Wm2 + l * 4);
    float p = fmaxf(a.x + b.x, 0.f) * w.x + fmaxf(a.y + b.y, 0.f) * w.y
            + fmaxf(a.z + b.z, 0.f) * w.z + fmaxf(a.w + b.w, 0.f) * w.w;
    p += __shfl_xor(p, 4);
    p += __shfl_xor(p, 2);
    p += __shfl_xor(p, 1);
    if (l == 0) out[e] = p + bm2[0];
}

extern "C" void kernel_launch(void* const* d_in, const int* in_sizes, int n_in,
                              void* d_out, int out_size, void* d_ws, size_t ws_size,
                              hipStream_t stream)
{
    const float* x   = (const float*)d_in[0];
    const int*   ei  = (const int*)d_in[1];
    const float* W0  = (const float*)d_in[2];
    const float* b0  = (const float*)d_in[3];
    const float* W1  = (const float*)d_in[4];
    const float* as1 = (const float*)d_in[5];
    const float* ad1 = (const float*)d_in[6];
    const float* b1  = (const float*)d_in[7];
    const float* W2  = (const float*)d_in[8];
    const float* as2 = (const float*)d_in[9];
    const float* ad2 = (const float*)d_in[10];
    const float* b2  = (const float*)d_in[11];
    const float* W3  = (const float*)d_in[12];
    const float* as3 = (const float*)d_in[13];
    const float* ad3 = (const float*)d_in[14];
    const float* b3  = (const float*)d_in[15];
    const float* Wm1 = (const float*)d_in[16];
    const float* bm1 = (const float*)d_in[17];
    const float* Wm2 = (const float*)d_in[18];
    const float* bm2 = (const float*)d_in[19];
    float* out = (float*)d_out;

    const int N = in_sizes[0] / 128;
    const int E = in_sizes[1] / 2;
    const int Etot = E + N;

    // Workspace layout
    float* ws = (float*)d_ws;
    float* A       = ws;                        // N x 64
    float* B       = A + (size_t)N * 64;        // N x 64
    float* C       = B + (size_t)N * 64;        // N x 64
    float* alpha_s = C + (size_t)N * 64;        // N
    float* alpha_d = alpha_s + N;               // N
    int* counts    = (int*)(alpha_d + N);       // N
    int* cursor    = counts + N;                // N
    int* row_ptr   = cursor + N;                // N + 1
    int* cols      = row_ptr + N + 1;           // E + N

    const int gNode64 = (N + 63) / 64;
    const int gN      = (N + 255) / 256;
    const int gE      = (E + 255) / 256;
    const int gFill   = (Etot + 255) / 256;
    const int gGather = (N + 15) / 16;
    const int gMlp    = (E * 8 + 255) / 256;

    // ---- Build CSR by dst (edge set identical for all 3 layers) ----
    csr_init<<<gN, 256, 0, stream>>>(counts, N);
    csr_count<<<gE, 256, 0, stream>>>(ei, counts, E);
    csr_scan<<<1, 1024, 0, stream>>>(counts, row_ptr, cursor, N);
    csr_fill<<<gFill, 256, 0, stream>>>(ei, cursor, cols, E, N);

    // h0 = x @ W0 + b0  -> A (N x 32)
    gemm_kernel<128, 32, false, false><<<gNode64, 256, 0, stream>>>(
        x, W0, b0, A, nullptr, nullptr, nullptr, nullptr, N);

    // ---- GAT layer 1: in A(32) -> h B(64) -> out C ----
    gemm_kernel<32, 64, false, true><<<gNode64, 256, 0, stream>>>(
        A, W1, nullptr, B, as1, ad1, alpha_s, alpha_d, N);
    gat_gather<true><<<gGather, 256, 0, stream>>>(
        row_ptr, cols, B, alpha_s, alpha_d, b1, C, N);

    // ---- GAT layer 2: in C -> h B -> out A ----
    gemm_kernel<64, 64, false, true><<<gNode64, 256, 0, stream>>>(
        C, W2, nullptr, B, as2, ad2, alpha_s, alpha_d, N);
    gat_gather<true><<<gGather, 256, 0, stream>>>(
        row_ptr, cols, B, alpha_s, alpha_d, b2, A, N);

    // ---- GAT layer 3: in A -> h B -> out C (no relu) ----
    gemm_kernel<64, 64, false, true><<<gNode64, 256, 0, stream>>>(
        A, W3, nullptr, B, as3, ad3, alpha_s, alpha_d, N);
    gat_gather<false><<<gGather, 256, 0, stream>>>(
        row_ptr, cols, B, alpha_s, alpha_d, b3, C, N);

    // ---- Final MLP, factorized over nodes ----
    float* Psrc = A;
    float* Pdst = A + (size_t)N * 32;
    gemm_kernel<64, 32, false, false><<<gNode64, 256, 0, stream>>>(
        C, Wm1, bm1, Psrc, nullptr, nullptr, nullptr, nullptr, N);
    gemm_kernel<64, 32, false, false><<<gNode64, 256, 0, stream>>>(
        C, Wm1 + 64 * 32, nullptr, Pdst, nullptr, nullptr, nullptr, nullptr, N);

    edge_mlp<<<gMlp, 256, 0, stream>>>(ei, Psrc, Pdst, Wm2, bm2, out, E);
}

// Round 4
// 902.639 us; speedup vs baseline: 2.2942x; 1.2402x over previous
//
#include <hip/hip_runtime.h>
#include <hip/hip_bf16.h>
#include <math.h>

// ---------------------------------------------------------------------------
// GNN: lin(128->32) -> 3x GATConv(heads=1, self-loops) -> edge MLP
// R1: CSR-by-dst built once; per-layer fused gather (no atomics in hot path).
// R3: multi-block hierarchical scan (old single-block csr_scan was 230us at
//     0.15% occupancy = 20% of total runtime).
// ---------------------------------------------------------------------------

// Tiled GEMM: out[n x M] = in[n x K] @ W[K x M] (+bias) (+relu)
// Optionally computes per-node alpha_src = h . avec_s, alpha_dst = h . avec_d.
template<int K, int M, bool RELU, bool ALPHA>
__global__ __launch_bounds__(256) void gemm_kernel(
    const float* __restrict__ in, const float* __restrict__ W,
    const float* __restrict__ bias, float* __restrict__ out,
    const float* __restrict__ avec_s, const float* __restrict__ avec_d,
    float* __restrict__ alpha_s, float* __restrict__ alpha_d, int n)
{
    __shared__ float sW[K][M];
    __shared__ float sX[64][K + 1];   // +1 pad: kill bank conflicts

    for (int i = threadIdx.x; i < K * M; i += 256)
        sW[i / M][i % M] = W[i];

    const int base = blockIdx.x * 64;
    for (int i = threadIdx.x; i < 64 * K; i += 256) {
        int r = i / K, c = i % K;
        int node = base + r;
        sX[r][c] = (node < n) ? in[(size_t)node * K + c] : 0.f;
    }
    __syncthreads();

    const int r  = threadIdx.x & 63;
    const int cg = threadIdx.x >> 6;       // 0..3
    constexpr int CPT = M / 4;             // cols per thread
    const int c0 = cg * CPT;

    float acc[CPT];
    #pragma unroll
    for (int j = 0; j < CPT; ++j) acc[j] = 0.f;

    #pragma unroll 4
    for (int k = 0; k < K; ++k) {
        float xv = sX[r][k];
        #pragma unroll
        for (int j = 0; j < CPT; ++j) acc[j] = fmaf(xv, sW[k][c0 + j], acc[j]);
    }

    const int node = base + r;
    if (node < n) {
        #pragma unroll
        for (int j = 0; j < CPT; ++j) {
            float v = acc[j] + (bias ? bias[c0 + j] : 0.f);
            if (RELU) v = fmaxf(v, 0.f);
            acc[j] = v;
            out[(size_t)node * M + c0 + j] = v;
        }
    }

    if constexpr (ALPHA) {
        __shared__ float sAS[4][64];
        __shared__ float sAD[4][64];
        float ps = 0.f, pd = 0.f;
        #pragma unroll
        for (int j = 0; j < CPT; ++j) {
            ps = fmaf(acc[j], avec_s[c0 + j], ps);
            pd = fmaf(acc[j], avec_d[c0 + j], pd);
        }
        sAS[cg][r] = ps;
        sAD[cg][r] = pd;
        __syncthreads();
        if (threadIdx.x < 64 && node < n) {
            alpha_s[node] = sAS[0][r] + sAS[1][r] + sAS[2][r] + sAS[3][r];
            alpha_d[node] = sAD[0][r] + sAD[1][r] + sAD[2][r] + sAD[3][r];
        }
    }
}

// ---- CSR build (once per launch; edge set shared by all 3 GAT layers) ----

constexpr int SCAN_CHUNK = 2048;   // elements per block (256 thr x 8)

// counts[i] = 1 (self loop)
__global__ void csr_init(int* __restrict__ counts, int n) {
    int i = blockIdx.x * 256 + threadIdx.x;
    if (i < n) counts[i] = 1;
}

__global__ void csr_count(const int* __restrict__ ei, int* __restrict__ counts, int E) {
    int i = blockIdx.x * 256 + threadIdx.x;
    if (i < E) atomicAdd(counts + ei[E + i], 1);
}

// Phase A: per-block sum of counts over its 2048-element chunk.
__global__ __launch_bounds__(256) void scan_partial(
    const int* __restrict__ counts, int* __restrict__ bsums, int n)
{
    const int base = blockIdx.x * SCAN_CHUNK + threadIdx.x * 8;
    int s = 0;
    #pragma unroll
    for (int j = 0; j < 8; ++j) {
        int i = base + j;
        if (i < n) s += counts[i];
    }
    s += __shfl_xor(s, 1);  s += __shfl_xor(s, 2);
    s += __shfl_xor(s, 4);  s += __shfl_xor(s, 8);
    s += __shfl_xor(s, 16); s += __shfl_xor(s, 32);
    __shared__ int red[4];
    if ((threadIdx.x & 63) == 0) red[threadIdx.x >> 6] = s;
    __syncthreads();
    if (threadIdx.x == 0) bsums[blockIdx.x] = red[0] + red[1] + red[2] + red[3];
}

// Phase B: single-block exclusive scan of the block sums (nb <= 256).
__global__ __launch_bounds__(256) void scan_bsums(int* __restrict__ bsums, int nb)
{
    __shared__ int sh[256];
    const int t = threadIdx.x;
    sh[t] = (t < nb) ? bsums[t] : 0;
    __syncthreads();
    for (int off = 1; off < 256; off <<= 1) {
        int v = (t >= off) ? sh[t - off] : 0;
        __syncthreads();
        sh[t] += v;
        __syncthreads();
    }
    if (t < nb) bsums[t] = (t == 0) ? 0 : sh[t - 1];   // exclusive
}

// Phase C: local scan + block offset -> row_ptr, cursor. row_ptr[n] = etot.
__global__ __launch_bounds__(256) void scan_final(
    const int* __restrict__ counts, const int* __restrict__ bsums,
    int* __restrict__ row_ptr, int* __restrict__ cursor, int n, int etot)
{
    __shared__ int tsum[256];
    const int t = threadIdx.x;
    const int base = blockIdx.x * SCAN_CHUNK + t * 8;
    int loc[8];
    int s = 0;
    #pragma unroll
    for (int j = 0; j < 8; ++j) {
        int i = base + j;
        loc[j] = (i < n) ? counts[i] : 0;
        s += loc[j];
    }
    tsum[t] = s;
    __syncthreads();
    for (int off = 1; off < 256; off <<= 1) {
        int v = (t >= off) ? tsum[t - off] : 0;
        __syncthreads();
        tsum[t] += v;
        __syncthreads();
    }
    int off = bsums[blockIdx.x] + ((t == 0) ? 0 : tsum[t - 1]);
    #pragma unroll
    for (int j = 0; j < 8; ++j) {
        int i = base + j;
        if (i < n) { row_ptr[i] = off; cursor[i] = off; off += loc[j]; }
    }
    if (blockIdx.x == 0 && t == 0) row_ptr[n] = etot;
}

// Scatter src ids into CSR order (edges then self-loops).
__global__ void csr_fill(const int* __restrict__ ei, int* __restrict__ cursor,
                         int* __restrict__ cols, int E, int n)
{
    int i = blockIdx.x * 256 + threadIdx.x;
    int total = E + n;
    if (i >= total) return;
    int s, d;
    if (i < E) { s = ei[i]; d = ei[E + i]; }
    else       { s = d = i - E; }
    int pos = atomicAdd(cursor + d, 1);
    cols[pos] = s;
}

// ---- Fused GAT aggregation: max + softmax + weighted gather + bias(+relu) ----
// 16 lanes per dst node, 4 cols each (float4).
template<bool RELU>
__global__ __launch_bounds__(256) void gat_gather(
    const int* __restrict__ row_ptr, const int* __restrict__ cols,
    const float* __restrict__ h, const float* __restrict__ as_,
    const float* __restrict__ ad_, const float* __restrict__ bias,
    float* __restrict__ out, int n)
{
    const int g = blockIdx.x * 16 + (threadIdx.x >> 4);   // dst node
    const int l = threadIdx.x & 15;
    if (g >= n) return;
    const int rp0 = row_ptr[g], rp1 = row_ptr[g + 1];
    const float adv = ad_[g];

    // pass 1: segment max (lane-parallel over edges)
    float amax = -1e30f;
    for (int i = rp0 + l; i < rp1; i += 16) {
        float lg = as_[cols[i]] + adv;
        lg = (lg >= 0.f) ? lg : 0.2f * lg;
        amax = fmaxf(amax, lg);
    }
    amax = fmaxf(amax, __shfl_xor(amax, 1));
    amax = fmaxf(amax, __shfl_xor(amax, 2));
    amax = fmaxf(amax, __shfl_xor(amax, 4));
    amax = fmaxf(amax, __shfl_xor(amax, 8));

    // pass 2: exp-weighted accumulate (serial over edges, coalesced h loads)
    float den = 0.f;
    float4 acc = make_float4(0.f, 0.f, 0.f, 0.f);
    for (int i = rp0; i < rp1; ++i) {
        int c = cols[i];                    // same addr across group: broadcast
        float lg = as_[c] + adv;
        lg = (lg >= 0.f) ? lg : 0.2f * lg;
        float ex = __expf(lg - amax);
        den += ex;
        float4 hv = *(const float4*)(h + (size_t)c * 64 + l * 4);
        acc.x = fmaf(ex, hv.x, acc.x);
        acc.y = fmaf(ex, hv.y, acc.y);
        acc.z = fmaf(ex, hv.z, acc.z);
        acc.w = fmaf(ex, hv.w, acc.w);
    }
    float inv = 1.f / (den + 1e-16f);
    float4 o;
    o.x = acc.x * inv + bias[l * 4 + 0];
    o.y = acc.y * inv + bias[l * 4 + 1];
    o.z = acc.z * inv + bias[l * 4 + 2];
    o.w = acc.w * inv + bias[l * 4 + 3];
    if (RELU) {
        o.x = fmaxf(o.x, 0.f); o.y = fmaxf(o.y, 0.f);
        o.z = fmaxf(o.z, 0.f); o.w = fmaxf(o.w, 0.f);
    }
    *(float4*)(out + (size_t)g * 64 + l * 4) = o;
}

// Final edge MLP: out[e] = relu(Ps[s] + Pd[d]) . Wm2 + bm2, 8 lanes/edge.
__global__ __launch_bounds__(256) void edge_mlp(
    const int* __restrict__ ei, const float* __restrict__ ps,
    const float* __restrict__ pd, const float* __restrict__ Wm2,
    const float* __restrict__ bm2, float* __restrict__ out, int E)
{
    int tid = blockIdx.x * 256 + threadIdx.x;
    int e = tid >> 3;
    int l = tid & 7;
    if (e >= E) return;
    int s = ei[e], d = ei[E + e];
    float4 a = *(const float4*)(ps + (size_t)s * 32 + l * 4);
    float4 b = *(const float4*)(pd + (size_t)d * 32 + l * 4);
    float4 w = *(const float4*)(Wm2 + l * 4);
    float p = fmaxf(a.x + b.x, 0.f) * w.x + fmaxf(a.y + b.y, 0.f) * w.y
            + fmaxf(a.z + b.z, 0.f) * w.z + fmaxf(a.w + b.w, 0.f) * w.w;
    p += __shfl_xor(p, 4);
    p += __shfl_xor(p, 2);
    p += __shfl_xor(p, 1);
    if (l == 0) out[e] = p + bm2[0];
}

extern "C" void kernel_launch(void* const* d_in, const int* in_sizes, int n_in,
                              void* d_out, int out_size, void* d_ws, size_t ws_size,
                              hipStream_t stream)
{
    const float* x   = (const float*)d_in[0];
    const int*   ei  = (const int*)d_in[1];
    const float* W0  = (const float*)d_in[2];
    const float* b0  = (const float*)d_in[3];
    const float* W1  = (const float*)d_in[4];
    const float* as1 = (const float*)d_in[5];
    const float* ad1 = (const float*)d_in[6];
    const float* b1  = (const float*)d_in[7];
    const float* W2  = (const float*)d_in[8];
    const float* as2 = (const float*)d_in[9];
    const float* ad2 = (const float*)d_in[10];
    const float* b2  = (const float*)d_in[11];
    const float* W3  = (const float*)d_in[12];
    const float* as3 = (const float*)d_in[13];
    const float* ad3 = (const float*)d_in[14];
    const float* b3  = (const float*)d_in[15];
    const float* Wm1 = (const float*)d_in[16];
    const float* bm1 = (const float*)d_in[17];
    const float* Wm2 = (const float*)d_in[18];
    const float* bm2 = (const float*)d_in[19];
    float* out = (float*)d_out;

    const int N = in_sizes[0] / 128;
    const int E = in_sizes[1] / 2;
    const int Etot = E + N;

    // Workspace layout
    float* ws = (float*)d_ws;
    float* A       = ws;                        // N x 64
    float* B       = A + (size_t)N * 64;        // N x 64
    float* C       = B + (size_t)N * 64;        // N x 64
    float* alpha_s = C + (size_t)N * 64;        // N
    float* alpha_d = alpha_s + N;               // N
    int* counts    = (int*)(alpha_d + N);       // N
    int* cursor    = counts + N;                // N
    int* row_ptr   = cursor + N;                // N + 1
    int* cols      = row_ptr + N + 1;           // E + N
    int* bsums     = cols + Etot;               // ceil(N/2048)

    const int nScanBlocks = (N + SCAN_CHUNK - 1) / SCAN_CHUNK;  // 49 for N=100k
    const int gNode64 = (N + 63) / 64;
    const int gN      = (N + 255) / 256;
    const int gE      = (E + 255) / 256;
    const int gFill   = (Etot + 255) / 256;
    const int gGather = (N + 15) / 16;
    const int gMlp    = (E * 8 + 255) / 256;

    // ---- Build CSR by dst (edge set identical for all 3 layers) ----
    csr_init<<<gN, 256, 0, stream>>>(counts, N);
    csr_count<<<gE, 256, 0, stream>>>(ei, counts, E);
    scan_partial<<<nScanBlocks, 256, 0, stream>>>(counts, bsums, N);
    scan_bsums<<<1, 256, 0, stream>>>(bsums, nScanBlocks);
    scan_final<<<nScanBlocks, 256, 0, stream>>>(counts, bsums, row_ptr, cursor, N, Etot);
    csr_fill<<<gFill, 256, 0, stream>>>(ei, cursor, cols, E, N);

    // h0 = x @ W0 + b0  -> A (N x 32)
    gemm_kernel<128, 32, false, false><<<gNode64, 256, 0, stream>>>(
        x, W0, b0, A, nullptr, nullptr, nullptr, nullptr, N);

    // ---- GAT layer 1: in A(32) -> h B(64) -> out C ----
    gemm_kernel<32, 64, false, true><<<gNode64, 256, 0, stream>>>(
        A, W1, nullptr, B, as1, ad1, alpha_s, alpha_d, N);
    gat_gather<true><<<gGather, 256, 0, stream>>>(
        row_ptr, cols, B, alpha_s, alpha_d, b1, C, N);

    // ---- GAT layer 2: in C -> h B -> out A ----
    gemm_kernel<64, 64, false, true><<<gNode64, 256, 0, stream>>>(
        C, W2, nullptr, B, as2, ad2, alpha_s, alpha_d, N);
    gat_gather<true><<<gGather, 256, 0, stream>>>(
        row_ptr, cols, B, alpha_s, alpha_d, b2, A, N);

    // ---- GAT layer 3: in A -> h B -> out C (no relu) ----
    gemm_kernel<64, 64, false, true><<<gNode64, 256, 0, stream>>>(
        A, W3, nullptr, B, as3, ad3, alpha_s, alpha_d, N);
    gat_gather<false><<<gGather, 256, 0, stream>>>(
        row_ptr, cols, B, alpha_s, alpha_d, b3, C, N);

    // ---- Final MLP, factorized over nodes ----
    float* Psrc = A;
    float* Pdst = A + (size_t)N * 32;
    gemm_kernel<64, 32, false, false><<<gNode64, 256, 0, stream>>>(
        C, Wm1, bm1, Psrc, nullptr, nullptr, nullptr, nullptr, N);
    gemm_kernel<64, 32, false, false><<<gNode64, 256, 0, stream>>>(
        C, Wm1 + 64 * 32, nullptr, Pdst, nullptr, nullptr, nullptr, nullptr, N);

    edge_mlp<<<gMlp, 256, 0, stream>>>(ei, Psrc, Pdst, Wm2, bm2, out, E);
}

// Round 5
// 742.181 us; speedup vs baseline: 2.7902x; 1.2162x over previous
//
#include <hip/hip_runtime.h>
#include <hip/hip_bf16.h>
#include <math.h>

// ---------------------------------------------------------------------------
// GNN: lin(128->32) -> 3x GATConv(heads=1, self-loops) -> edge MLP
// R1: CSR-by-dst built once; per-layer fused gather (no atomics in hot path).
// R3: multi-block hierarchical scan.
// R4: bucketed counting-sort CSR build (csr_fill had 16x write amplification:
//     108MB for 6.8MB payload). row_ptr now derived per-bucket in LDS; the
//     global counts array, csr_init, csr_count and the counts-scan are gone.
//     Final two GEMMs fused into gemm_dual.
// ---------------------------------------------------------------------------

constexpr int SCAN_CHUNK   = 2048;   // elements per scan block (256 thr x 8)
constexpr int SORT_EPB     = 16384;  // edges per sort block
constexpr int BUCKET_SHIFT = 8;      // 256 dsts per bucket
constexpr int MAX_BUCKETS  = 1024;   // supports N <= 262144

// Tiled GEMM: out[n x M] = in[n x K] @ W[K x M] (+bias) (+relu)
// Optionally computes per-node alpha_src = h . avec_s, alpha_dst = h . avec_d.
template<int K, int M, bool RELU, bool ALPHA>
__global__ __launch_bounds__(256) void gemm_kernel(
    const float* __restrict__ in, const float* __restrict__ W,
    const float* __restrict__ bias, float* __restrict__ out,
    const float* __restrict__ avec_s, const float* __restrict__ avec_d,
    float* __restrict__ alpha_s, float* __restrict__ alpha_d, int n)
{
    __shared__ float sW[K][M];
    __shared__ float sX[64][K + 1];   // +1 pad: kill bank conflicts

    for (int i = threadIdx.x; i < K * M; i += 256)
        sW[i / M][i % M] = W[i];

    const int base = blockIdx.x * 64;
    for (int i = threadIdx.x; i < 64 * K; i += 256) {
        int r = i / K, c = i % K;
        int node = base + r;
        sX[r][c] = (node < n) ? in[(size_t)node * K + c] : 0.f;
    }
    __syncthreads();

    const int r  = threadIdx.x & 63;
    const int cg = threadIdx.x >> 6;       // 0..3
    constexpr int CPT = M / 4;             // cols per thread
    const int c0 = cg * CPT;

    float acc[CPT];
    #pragma unroll
    for (int j = 0; j < CPT; ++j) acc[j] = 0.f;

    #pragma unroll 4
    for (int k = 0; k < K; ++k) {
        float xv = sX[r][k];
        #pragma unroll
        for (int j = 0; j < CPT; ++j) acc[j] = fmaf(xv, sW[k][c0 + j], acc[j]);
    }

    const int node = base + r;
    if (node < n) {
        #pragma unroll
        for (int j = 0; j < CPT; ++j) {
            float v = acc[j] + (bias ? bias[c0 + j] : 0.f);
            if (RELU) v = fmaxf(v, 0.f);
            acc[j] = v;
            out[(size_t)node * M + c0 + j] = v;
        }
    }

    if constexpr (ALPHA) {
        __shared__ float sAS[4][64];
        __shared__ float sAD[4][64];
        float ps = 0.f, pd = 0.f;
        #pragma unroll
        for (int j = 0; j < CPT; ++j) {
            ps = fmaf(acc[j], avec_s[c0 + j], ps);
            pd = fmaf(acc[j], avec_d[c0 + j], pd);
        }
        sAS[cg][r] = ps;
        sAD[cg][r] = pd;
        __syncthreads();
        if (threadIdx.x < 64 && node < n) {
            alpha_s[node] = sAS[0][r] + sAS[1][r] + sAS[2][r] + sAS[3][r];
            alpha_d[node] = sAD[0][r] + sAD[1][r] + sAD[2][r] + sAD[3][r];
        }
    }
}

// Fused final GEMM: Psrc = in@Wm1[0:64]+bm1, Pdst = in@Wm1[64:128]. K=64.
__global__ __launch_bounds__(256) void gemm_dual(
    const float* __restrict__ in, const float* __restrict__ Wm1,
    const float* __restrict__ bm1, float* __restrict__ ps,
    float* __restrict__ pd, int n)
{
    __shared__ float sW[128][32];
    __shared__ float sX[64][65];
    for (int i = threadIdx.x; i < 128 * 32; i += 256)
        sW[i >> 5][i & 31] = Wm1[i];
    const int base = blockIdx.x * 64;
    for (int i = threadIdx.x; i < 64 * 64; i += 256) {
        int r = i >> 6, c = i & 63;
        int node = base + r;
        sX[r][c] = (node < n) ? in[(size_t)node * 64 + c] : 0.f;
    }
    __syncthreads();
    const int r  = threadIdx.x & 63;
    const int cg = threadIdx.x >> 6;
    const int c0 = cg * 8;
    float a1[8], a2[8];
    #pragma unroll
    for (int j = 0; j < 8; ++j) { a1[j] = 0.f; a2[j] = 0.f; }
    #pragma unroll 4
    for (int k = 0; k < 64; ++k) {
        float xv = sX[r][k];
        #pragma unroll
        for (int j = 0; j < 8; ++j) {
            a1[j] = fmaf(xv, sW[k][c0 + j], a1[j]);
            a2[j] = fmaf(xv, sW[64 + k][c0 + j], a2[j]);
        }
    }
    const int node = base + r;
    if (node < n) {
        #pragma unroll
        for (int j = 0; j < 8; ++j) {
            ps[(size_t)node * 32 + c0 + j] = a1[j] + bm1[c0 + j];
            pd[(size_t)node * 32 + c0 + j] = a2[j];
        }
    }
}

// ---- CSR build via bucketed counting sort (bucket = dst >> BUCKET_SHIFT) ----

// S1: per-(bucket, block) histogram. hist layout: hist[k * nsb + b].
__global__ __launch_bounds__(256) void sort_hist(
    const int* __restrict__ ei, int* __restrict__ hist,
    int E, int etot, int nb, int nsb)
{
    __shared__ int h[MAX_BUCKETS];
    for (int i = threadIdx.x; i < nb; i += 256) h[i] = 0;
    __syncthreads();
    const int base = blockIdx.x * SORT_EPB;
    const int end  = min(base + SORT_EPB, etot);
    for (int i = base + threadIdx.x; i < end; i += 256) {
        int d = (i < E) ? ei[E + i] : (i - E);
        atomicAdd(&h[d >> BUCKET_SHIFT], 1);
    }
    __syncthreads();
    for (int k = threadIdx.x; k < nb; k += 256)
        hist[k * nsb + blockIdx.x] = h[k];
}

// Generic 3-phase exclusive scan (len <= 256 * SCAN_CHUNK)
__global__ __launch_bounds__(256) void scan_partial(
    const int* __restrict__ in, int* __restrict__ bsums, int len)
{
    const int base = blockIdx.x * SCAN_CHUNK + threadIdx.x * 8;
    int s = 0;
    #pragma unroll
    for (int j = 0; j < 8; ++j) {
        int i = base + j;
        if (i < len) s += in[i];
    }
    s += __shfl_xor(s, 1);  s += __shfl_xor(s, 2);
    s += __shfl_xor(s, 4);  s += __shfl_xor(s, 8);
    s += __shfl_xor(s, 16); s += __shfl_xor(s, 32);
    __shared__ int red[4];
    if ((threadIdx.x & 63) == 0) red[threadIdx.x >> 6] = s;
    __syncthreads();
    if (threadIdx.x == 0) bsums[blockIdx.x] = red[0] + red[1] + red[2] + red[3];
}

__global__ __launch_bounds__(256) void scan_bsums(int* __restrict__ bsums, int nbk)
{
    __shared__ int sh[256];
    const int t = threadIdx.x;
    sh[t] = (t < nbk) ? bsums[t] : 0;
    __syncthreads();
    for (int off = 1; off < 256; off <<= 1) {
        int v = (t >= off) ? sh[t - off] : 0;
        __syncthreads();
        sh[t] += v;
        __syncthreads();
    }
    if (t < nbk) bsums[t] = (t == 0) ? 0 : sh[t - 1];   // exclusive
}

__global__ __launch_bounds__(256) void scan_final_g(
    const int* __restrict__ in, const int* __restrict__ bsums,
    int* __restrict__ out, int len)
{
    __shared__ int tsum[256];
    const int t = threadIdx.x;
    const int base = blockIdx.x * SCAN_CHUNK + t * 8;
    int loc[8];
    int s = 0;
    #pragma unroll
    for (int j = 0; j < 8; ++j) {
        int i = base + j;
        loc[j] = (i < len) ? in[i] : 0;
        s += loc[j];
    }
    tsum[t] = s;
    __syncthreads();
    for (int off = 1; off < 256; off <<= 1) {
        int v = (t >= off) ? tsum[t - off] : 0;
        __syncthreads();
        tsum[t] += v;
        __syncthreads();
    }
    int off = bsums[blockIdx.x] + ((t == 0) ? 0 : tsum[t - 1]);
    #pragma unroll
    for (int j = 0; j < 8; ++j) {
        int i = base + j;
        if (i < len) { out[i] = off; off += loc[j]; }
    }
}

// S2: scatter (src,dst) pairs into bucket-sorted staging (dense runs).
__global__ __launch_bounds__(256) void sort_scatter(
    const int* __restrict__ ei, const int* __restrict__ hist_scan,
    uint2* __restrict__ staged, int E, int etot, int nb, int nsb)
{
    __shared__ int cur[MAX_BUCKETS];
    for (int k = threadIdx.x; k < nb; k += 256)
        cur[k] = hist_scan[k * nsb + blockIdx.x];
    __syncthreads();
    const int base = blockIdx.x * SORT_EPB;
    const int end  = min(base + SORT_EPB, etot);
    for (int i = base + threadIdx.x; i < end; i += 256) {
        int s, d;
        if (i < E) { s = ei[i]; d = ei[E + i]; }
        else       { s = d = i - E; }
        int pos = atomicAdd(&cur[d >> BUCKET_SHIFT], 1);
        staged[pos] = make_uint2((unsigned)s, (unsigned)d);
    }
}

// S3: per-bucket: LDS dst-count -> prefix -> row_ptr (dense write) -> fill cols.
__global__ __launch_bounds__(256) void bucket_fill(
    const uint2* __restrict__ staged, const int* __restrict__ hist_scan,
    int* __restrict__ row_ptr, int* __restrict__ cols,
    int n, int etot, int nb, int nsb)
{
    __shared__ int cnt[256], scn[256], cur[256];
    const int k = blockIdx.x;
    const int dbase = k << BUCKET_SHIFT;
    const int ndst = min(256, n - dbase);
    const int bs = hist_scan[k * nsb];
    const int be = (k + 1 < nb) ? hist_scan[(k + 1) * nsb] : etot;
    const int t = threadIdx.x;
    cnt[t] = 0;
    __syncthreads();
    for (int i = bs + t; i < be; i += 256)
        atomicAdd(&cnt[staged[i].y - dbase], 1);
    __syncthreads();
    scn[t] = cnt[t];
    __syncthreads();
    for (int off = 1; off < 256; off <<= 1) {
        int v = (t >= off) ? scn[t - off] : 0;
        __syncthreads();
        scn[t] += v;
        __syncthreads();
    }
    const int rp = bs + scn[t] - cnt[t];   // exclusive prefix
    if (t < ndst) row_ptr[dbase + t] = rp;
    cur[t] = rp;
    __syncthreads();
    for (int i = bs + t; i < be; i += 256) {
        uint2 e = staged[i];
        int pos = atomicAdd(&cur[e.y - dbase], 1);
        cols[pos] = (int)e.x;
    }
    if (k == nb - 1 && t == 0) row_ptr[n] = etot;
}

// ---- Fused GAT aggregation: max + softmax + weighted gather + bias(+relu) ----
// 16 lanes per dst node, 4 cols each (float4).
template<bool RELU>
__global__ __launch_bounds__(256) void gat_gather(
    const int* __restrict__ row_ptr, const int* __restrict__ cols,
    const float* __restrict__ h, const float* __restrict__ as_,
    const float* __restrict__ ad_, const float* __restrict__ bias,
    float* __restrict__ out, int n)
{
    const int g = blockIdx.x * 16 + (threadIdx.x >> 4);   // dst node
    const int l = threadIdx.x & 15;
    if (g >= n) return;
    const int rp0 = row_ptr[g], rp1 = row_ptr[g + 1];
    const float adv = ad_[g];

    // pass 1: segment max (lane-parallel over edges)
    float amax = -1e30f;
    for (int i = rp0 + l; i < rp1; i += 16) {
        float lg = as_[cols[i]] + adv;
        lg = (lg >= 0.f) ? lg : 0.2f * lg;
        amax = fmaxf(amax, lg);
    }
    amax = fmaxf(amax, __shfl_xor(amax, 1));
    amax = fmaxf(amax, __shfl_xor(amax, 2));
    amax = fmaxf(amax, __shfl_xor(amax, 4));
    amax = fmaxf(amax, __shfl_xor(amax, 8));

    // pass 2: exp-weighted accumulate (serial over edges, coalesced h loads)
    float den = 0.f;
    float4 acc = make_float4(0.f, 0.f, 0.f, 0.f);
    for (int i = rp0; i < rp1; ++i) {
        int c = cols[i];                    // same addr across group: broadcast
        float lg = as_[c] + adv;
        lg = (lg >= 0.f) ? lg : 0.2f * lg;
        float ex = __expf(lg - amax);
        den += ex;
        float4 hv = *(const float4*)(h + (size_t)c * 64 + l * 4);
        acc.x = fmaf(ex, hv.x, acc.x);
        acc.y = fmaf(ex, hv.y, acc.y);
        acc.z = fmaf(ex, hv.z, acc.z);
        acc.w = fmaf(ex, hv.w, acc.w);
    }
    float inv = 1.f / (den + 1e-16f);
    float4 o;
    o.x = acc.x * inv + bias[l * 4 + 0];
    o.y = acc.y * inv + bias[l * 4 + 1];
    o.z = acc.z * inv + bias[l * 4 + 2];
    o.w = acc.w * inv + bias[l * 4 + 3];
    if (RELU) {
        o.x = fmaxf(o.x, 0.f); o.y = fmaxf(o.y, 0.f);
        o.z = fmaxf(o.z, 0.f); o.w = fmaxf(o.w, 0.f);
    }
    *(float4*)(out + (size_t)g * 64 + l * 4) = o;
}

// Final edge MLP: out[e] = relu(Ps[s] + Pd[d]) . Wm2 + bm2, 8 lanes/edge.
__global__ __launch_bounds__(256) void edge_mlp(
    const int* __restrict__ ei, const float* __restrict__ ps,
    const float* __restrict__ pd, const float* __restrict__ Wm2,
    const float* __restrict__ bm2, float* __restrict__ out, int E)
{
    int tid = blockIdx.x * 256 + threadIdx.x;
    int e = tid >> 3;
    int l = tid & 7;
    if (e >= E) return;
    int s = ei[e], d = ei[E + e];
    float4 a = *(const float4*)(ps + (size_t)s * 32 + l * 4);
    float4 b = *(const float4*)(pd + (size_t)d * 32 + l * 4);
    float4 w = *(const float4*)(Wm2 + l * 4);
    float p = fmaxf(a.x + b.x, 0.f) * w.x + fmaxf(a.y + b.y, 0.f) * w.y
            + fmaxf(a.z + b.z, 0.f) * w.z + fmaxf(a.w + b.w, 0.f) * w.w;
    p += __shfl_xor(p, 4);
    p += __shfl_xor(p, 2);
    p += __shfl_xor(p, 1);
    if (l == 0) out[e] = p + bm2[0];
}

extern "C" void kernel_launch(void* const* d_in, const int* in_sizes, int n_in,
                              void* d_out, int out_size, void* d_ws, size_t ws_size,
                              hipStream_t stream)
{
    const float* x   = (const float*)d_in[0];
    const int*   ei  = (const int*)d_in[1];
    const float* W0  = (const float*)d_in[2];
    const float* b0  = (const float*)d_in[3];
    const float* W1  = (const float*)d_in[4];
    const float* as1 = (const float*)d_in[5];
    const float* ad1 = (const float*)d_in[6];
    const float* b1  = (const float*)d_in[7];
    const float* W2  = (const float*)d_in[8];
    const float* as2 = (const float*)d_in[9];
    const float* ad2 = (const float*)d_in[10];
    const float* b2  = (const float*)d_in[11];
    const float* W3  = (const float*)d_in[12];
    const float* as3 = (const float*)d_in[13];
    const float* ad3 = (const float*)d_in[14];
    const float* b3  = (const float*)d_in[15];
    const float* Wm1 = (const float*)d_in[16];
    const float* bm1 = (const float*)d_in[17];
    const float* Wm2 = (const float*)d_in[18];
    const float* bm2 = (const float*)d_in[19];
    float* out = (float*)d_out;

    const int N = in_sizes[0] / 128;
    const int E = in_sizes[1] / 2;
    const int Etot = E + N;

    // Workspace layout (persistent)
    float* ws = (float*)d_ws;
    float* A       = ws;                        // N x 64
    float* B       = A + (size_t)N * 64;        // N x 64
    float* C       = B + (size_t)N * 64;        // N x 64
    float* alpha_s = C + (size_t)N * 64;        // N
    float* alpha_d = alpha_s + N;               // N
    int* row_ptr   = (int*)(alpha_d + N);       // N + 1
    int* cols      = row_ptr + N + 1;           // Etot
    int* bsums     = cols + Etot;               // 256

    // CSR-build scratch aliased onto A/B (free until first GEMM)
    uint2* staged  = (uint2*)A;                 // Etot * 8B  (<= N*64*4B)
    const int nsb  = (Etot + SORT_EPB - 1) / SORT_EPB;
    const int nb   = (N + (1 << BUCKET_SHIFT) - 1) >> BUCKET_SHIFT;
    const int hlen = nb * nsb;
    int* hist      = (int*)B;                   // hlen
    int* hist_scan = hist + hlen;               // hlen

    const int nScanBlocks = (hlen + SCAN_CHUNK - 1) / SCAN_CHUNK;
    const int gNode64 = (N + 63) / 64;
    const int gGather = (N + 15) / 16;
    const int gMlp    = (E * 8 + 255) / 256;

    // ---- Build CSR by dst (edge set identical for all 3 layers) ----
    sort_hist<<<nsb, 256, 0, stream>>>(ei, hist, E, Etot, nb, nsb);
    scan_partial<<<nScanBlocks, 256, 0, stream>>>(hist, bsums, hlen);
    scan_bsums<<<1, 256, 0, stream>>>(bsums, nScanBlocks);
    scan_final_g<<<nScanBlocks, 256, 0, stream>>>(hist, bsums, hist_scan, hlen);
    sort_scatter<<<nsb, 256, 0, stream>>>(ei, hist_scan, staged, E, Etot, nb, nsb);
    bucket_fill<<<nb, 256, 0, stream>>>(staged, hist_scan, row_ptr, cols, N, Etot, nb, nsb);

    // h0 = x @ W0 + b0  -> A (N x 32)   [staged dead from here on]
    gemm_kernel<128, 32, false, false><<<gNode64, 256, 0, stream>>>(
        x, W0, b0, A, nullptr, nullptr, nullptr, nullptr, N);

    // ---- GAT layer 1: in A(32) -> h B(64) -> out C ----
    gemm_kernel<32, 64, false, true><<<gNode64, 256, 0, stream>>>(
        A, W1, nullptr, B, as1, ad1, alpha_s, alpha_d, N);
    gat_gather<true><<<gGather, 256, 0, stream>>>(
        row_ptr, cols, B, alpha_s, alpha_d, b1, C, N);

    // ---- GAT layer 2: in C -> h B -> out A ----
    gemm_kernel<64, 64, false, true><<<gNode64, 256, 0, stream>>>(
        C, W2, nullptr, B, as2, ad2, alpha_s, alpha_d, N);
    gat_gather<true><<<gGather, 256, 0, stream>>>(
        row_ptr, cols, B, alpha_s, alpha_d, b2, A, N);

    // ---- GAT layer 3: in A -> h B -> out C (no relu) ----
    gemm_kernel<64, 64, false, true><<<gNode64, 256, 0, stream>>>(
        A, W3, nullptr, B, as3, ad3, alpha_s, alpha_d, N);
    gat_gather<false><<<gGather, 256, 0, stream>>>(
        row_ptr, cols, B, alpha_s, alpha_d, b3, C, N);

    // ---- Final MLP, factorized over nodes (fused dual GEMM) ----
    float* Psrc = A;
    float* Pdst = A + (size_t)N * 32;
    gemm_dual<<<gNode64, 256, 0, stream>>>(C, Wm1, bm1, Psrc, Pdst, N);

    edge_mlp<<<gMlp, 256, 0, stream>>>(ei, Psrc, Pdst, Wm2, bm2, out, E);
}

// Round 7
// 656.817 us; speedup vs baseline: 3.1528x; 1.1300x over previous
//
#include <hip/hip_runtime.h>
#include <hip/hip_bf16.h>
#include <math.h>

// ---------------------------------------------------------------------------
// GNN: lin(128->32) -> 3x GATConv(heads=1, self-loops) -> edge MLP
// R1: CSR-by-dst built once; per-layer fused gather (no atomics in hot path).
// R3: multi-block hierarchical scan.
// R4: bucketed counting-sort CSR build; fused final dual GEMM.
// R5: gemm K-chunked (LDS 49.6->33KB, 2->4 blocks/CU) + float4 staging loads;
//     gat_gather single-pass (exp without max-shift: logits bounded <<88, the
//     shift cancels in ex/den exactly) + 2x unrolled MLP pipeline.
// R6: identical resubmit (R5 bench was GPUAcquisitionTimeout — no data).
// ---------------------------------------------------------------------------

constexpr int SCAN_CHUNK   = 2048;   // elements per scan block (256 thr x 8)
constexpr int SORT_EPB     = 16384;  // edges per sort block
constexpr int BUCKET_SHIFT = 8;      // 256 dsts per bucket
constexpr int MAX_BUCKETS  = 1024;   // supports N <= 262144

// Tiled GEMM: out[n x M] = in[n x K] @ W[K x M] (+bias) (+relu)
// K processed in 64-wide chunks; X staged via float4 loads.
// Optionally computes per-node alpha_src = h . avec_s, alpha_dst = h . avec_d.
template<int K, int M, bool RELU, bool ALPHA>
__global__ __launch_bounds__(256) void gemm_kernel(
    const float* __restrict__ in, const float* __restrict__ W,
    const float* __restrict__ bias, float* __restrict__ out,
    const float* __restrict__ avec_s, const float* __restrict__ avec_d,
    float* __restrict__ alpha_s, float* __restrict__ alpha_d, int n)
{
    constexpr int KC  = (K > 64) ? 64 : K;    // k-chunk width
    constexpr int NKB = K / KC;
    __shared__ float sW[K][M];
    __shared__ float sX[64][KC + 1];          // +1 pad: conflict-free reads

    for (int i = threadIdx.x; i < K * M; i += 256)
        sW[i / M][i % M] = W[i];

    const int base = blockIdx.x * 64;
    const int r  = threadIdx.x & 63;
    const int cg = threadIdx.x >> 6;          // 0..3
    constexpr int CPT = M / 4;                // cols per thread
    const int c0 = cg * CPT;

    float acc[CPT];
    #pragma unroll
    for (int j = 0; j < CPT; ++j) acc[j] = 0.f;

    for (int kb = 0; kb < NKB; ++kb) {
        __syncthreads();   // guards sW (first iter) / prev chunk reads
        // stage 64 x KC chunk with float4 loads (16B/lane, coalesced)
        for (int i = threadIdx.x; i < 64 * KC / 4; i += 256) {
            int rr = i / (KC / 4), c4 = (i % (KC / 4)) * 4;
            int node = base + rr;
            float4 v = (node < n)
                ? *(const float4*)(in + (size_t)node * K + kb * KC + c4)
                : make_float4(0.f, 0.f, 0.f, 0.f);
            sX[rr][c4 + 0] = v.x; sX[rr][c4 + 1] = v.y;
            sX[rr][c4 + 2] = v.z; sX[rr][c4 + 3] = v.w;
        }
        __syncthreads();
        #pragma unroll 4
        for (int k = 0; k < KC; ++k) {
            float xv = sX[r][k];
            #pragma unroll
            for (int j = 0; j < CPT; ++j)
                acc[j] = fmaf(xv, sW[kb * KC + k][c0 + j], acc[j]);
        }
    }

    const int node = base + r;
    if (node < n) {
        #pragma unroll
        for (int j = 0; j < CPT; ++j) {
            float v = acc[j] + (bias ? bias[c0 + j] : 0.f);
            if (RELU) v = fmaxf(v, 0.f);
            acc[j] = v;
            out[(size_t)node * M + c0 + j] = v;
        }
    }

    if constexpr (ALPHA) {
        __shared__ float sAS[4][64];
        __shared__ float sAD[4][64];
        float ps = 0.f, pd = 0.f;
        #pragma unroll
        for (int j = 0; j < CPT; ++j) {
            ps = fmaf(acc[j], avec_s[c0 + j], ps);
            pd = fmaf(acc[j], avec_d[c0 + j], pd);
        }
        sAS[cg][r] = ps;
        sAD[cg][r] = pd;
        __syncthreads();
        if (threadIdx.x < 64 && node < n) {
            alpha_s[node] = sAS[0][r] + sAS[1][r] + sAS[2][r] + sAS[3][r];
            alpha_d[node] = sAD[0][r] + sAD[1][r] + sAD[2][r] + sAD[3][r];
        }
    }
}

// Fused final GEMM: Psrc = in@Wm1[0:64]+bm1, Pdst = in@Wm1[64:128]. K=64.
__global__ __launch_bounds__(256) void gemm_dual(
    const float* __restrict__ in, const float* __restrict__ Wm1,
    const float* __restrict__ bm1, float* __restrict__ ps,
    float* __restrict__ pd, int n)
{
    __shared__ float sW[128][32];
    __shared__ float sX[64][65];
    for (int i = threadIdx.x; i < 128 * 32; i += 256)
        sW[i >> 5][i & 31] = Wm1[i];
    const int base = blockIdx.x * 64;
    for (int i = threadIdx.x; i < 64 * 16; i += 256) {
        int rr = i >> 4, c4 = (i & 15) * 4;
        int node = base + rr;
        float4 v = (node < n)
            ? *(const float4*)(in + (size_t)node * 64 + c4)
            : make_float4(0.f, 0.f, 0.f, 0.f);
        sX[rr][c4 + 0] = v.x; sX[rr][c4 + 1] = v.y;
        sX[rr][c4 + 2] = v.z; sX[rr][c4 + 3] = v.w;
    }
    __syncthreads();
    const int r  = threadIdx.x & 63;
    const int cg = threadIdx.x >> 6;
    const int c0 = cg * 8;
    float a1[8], a2[8];
    #pragma unroll
    for (int j = 0; j < 8; ++j) { a1[j] = 0.f; a2[j] = 0.f; }
    #pragma unroll 4
    for (int k = 0; k < 64; ++k) {
        float xv = sX[r][k];
        #pragma unroll
        for (int j = 0; j < 8; ++j) {
            a1[j] = fmaf(xv, sW[k][c0 + j], a1[j]);
            a2[j] = fmaf(xv, sW[64 + k][c0 + j], a2[j]);
        }
    }
    const int node = base + r;
    if (node < n) {
        #pragma unroll
        for (int j = 0; j < 8; ++j) {
            ps[(size_t)node * 32 + c0 + j] = a1[j] + bm1[c0 + j];
            pd[(size_t)node * 32 + c0 + j] = a2[j];
        }
    }
}

// ---- CSR build via bucketed counting sort (bucket = dst >> BUCKET_SHIFT) ----

// S1: per-(bucket, block) histogram. hist layout: hist[k * nsb + b].
__global__ __launch_bounds__(256) void sort_hist(
    const int* __restrict__ ei, int* __restrict__ hist,
    int E, int etot, int nb, int nsb)
{
    __shared__ int h[MAX_BUCKETS];
    for (int i = threadIdx.x; i < nb; i += 256) h[i] = 0;
    __syncthreads();
    const int base = blockIdx.x * SORT_EPB;
    const int end  = min(base + SORT_EPB, etot);
    for (int i = base + threadIdx.x; i < end; i += 256) {
        int d = (i < E) ? ei[E + i] : (i - E);
        atomicAdd(&h[d >> BUCKET_SHIFT], 1);
    }
    __syncthreads();
    for (int k = threadIdx.x; k < nb; k += 256)
        hist[k * nsb + blockIdx.x] = h[k];
}

// Generic 3-phase exclusive scan (len <= 256 * SCAN_CHUNK)
__global__ __launch_bounds__(256) void scan_partial(
    const int* __restrict__ in, int* __restrict__ bsums, int len)
{
    const int base = blockIdx.x * SCAN_CHUNK + threadIdx.x * 8;
    int s = 0;
    #pragma unroll
    for (int j = 0; j < 8; ++j) {
        int i = base + j;
        if (i < len) s += in[i];
    }
    s += __shfl_xor(s, 1);  s += __shfl_xor(s, 2);
    s += __shfl_xor(s, 4);  s += __shfl_xor(s, 8);
    s += __shfl_xor(s, 16); s += __shfl_xor(s, 32);
    __shared__ int red[4];
    if ((threadIdx.x & 63) == 0) red[threadIdx.x >> 6] = s;
    __syncthreads();
    if (threadIdx.x == 0) bsums[blockIdx.x] = red[0] + red[1] + red[2] + red[3];
}

__global__ __launch_bounds__(256) void scan_bsums(int* __restrict__ bsums, int nbk)
{
    __shared__ int sh[256];
    const int t = threadIdx.x;
    sh[t] = (t < nbk) ? bsums[t] : 0;
    __syncthreads();
    for (int off = 1; off < 256; off <<= 1) {
        int v = (t >= off) ? sh[t - off] : 0;
        __syncthreads();
        sh[t] += v;
        __syncthreads();
    }
    if (t < nbk) bsums[t] = (t == 0) ? 0 : sh[t - 1];   // exclusive
}

__global__ __launch_bounds__(256) void scan_final_g(
    const int* __restrict__ in, const int* __restrict__ bsums,
    int* __restrict__ out, int len)
{
    __shared__ int tsum[256];
    const int t = threadIdx.x;
    const int base = blockIdx.x * SCAN_CHUNK + t * 8;
    int loc[8];
    int s = 0;
    #pragma unroll
    for (int j = 0; j < 8; ++j) {
        int i = base + j;
        loc[j] = (i < len) ? in[i] : 0;
        s += loc[j];
    }
    tsum[t] = s;
    __syncthreads();
    for (int off = 1; off < 256; off <<= 1) {
        int v = (t >= off) ? tsum[t - off] : 0;
        __syncthreads();
        tsum[t] += v;
        __syncthreads();
    }
    int off = bsums[blockIdx.x] + ((t == 0) ? 0 : tsum[t - 1]);
    #pragma unroll
    for (int j = 0; j < 8; ++j) {
        int i = base + j;
        if (i < len) { out[i] = off; off += loc[j]; }
    }
}

// S2: scatter (src,dst) pairs into bucket-sorted staging (dense runs).
__global__ __launch_bounds__(256) void sort_scatter(
    const int* __restrict__ ei, const int* __restrict__ hist_scan,
    uint2* __restrict__ staged, int E, int etot, int nb, int nsb)
{
    __shared__ int cur[MAX_BUCKETS];
    for (int k = threadIdx.x; k < nb; k += 256)
        cur[k] = hist_scan[k * nsb + blockIdx.x];
    __syncthreads();
    const int base = blockIdx.x * SORT_EPB;
    const int end  = min(base + SORT_EPB, etot);
    for (int i = base + threadIdx.x; i < end; i += 256) {
        int s, d;
        if (i < E) { s = ei[i]; d = ei[E + i]; }
        else       { s = d = i - E; }
        int pos = atomicAdd(&cur[d >> BUCKET_SHIFT], 1);
        staged[pos] = make_uint2((unsigned)s, (unsigned)d);
    }
}

// S3: per-bucket: LDS dst-count -> prefix -> row_ptr (dense write) -> fill cols.
__global__ __launch_bounds__(256) void bucket_fill(
    const uint2* __restrict__ staged, const int* __restrict__ hist_scan,
    int* __restrict__ row_ptr, int* __restrict__ cols,
    int n, int etot, int nb, int nsb)
{
    __shared__ int cnt[256], scn[256], cur[256];
    const int k = blockIdx.x;
    const int dbase = k << BUCKET_SHIFT;
    const int ndst = min(256, n - dbase);
    const int bs = hist_scan[k * nsb];
    const int be = (k + 1 < nb) ? hist_scan[(k + 1) * nsb] : etot;
    const int t = threadIdx.x;
    cnt[t] = 0;
    __syncthreads();
    for (int i = bs + t; i < be; i += 256)
        atomicAdd(&cnt[staged[i].y - dbase], 1);
    __syncthreads();
    scn[t] = cnt[t];
    __syncthreads();
    for (int off = 1; off < 256; off <<= 1) {
        int v = (t >= off) ? scn[t - off] : 0;
        __syncthreads();
        scn[t] += v;
        __syncthreads();
    }
    const int rp = bs + scn[t] - cnt[t];   // exclusive prefix
    if (t < ndst) row_ptr[dbase + t] = rp;
    cur[t] = rp;
    __syncthreads();
    for (int i = bs + t; i < be; i += 256) {
        uint2 e = staged[i];
        int pos = atomicAdd(&cur[e.y - dbase], 1);
        cols[pos] = (int)e.x;
    }
    if (k == nb - 1 && t == 0) row_ptr[n] = etot;
}

// ---- Fused GAT aggregation: softmax + weighted gather + bias(+relu) ----
// Single pass, no max-shift (logits bounded far below fp32 exp overflow; the
// shift cancels exactly in ex/den). 16 lanes per dst node, float4 cols.
// 2x unrolled: both h-row loads issued before dependent exp math (MLP).
template<bool RELU>
__global__ __launch_bounds__(256) void gat_gather(
    const int* __restrict__ row_ptr, const int* __restrict__ cols,
    const float* __restrict__ h, const float* __restrict__ as_,
    const float* __restrict__ ad_, const float* __restrict__ bias,
    float* __restrict__ out, int n)
{
    const int g = blockIdx.x * 16 + (threadIdx.x >> 4);   // dst node
    const int l = threadIdx.x & 15;
    if (g >= n) return;
    const int rp0 = row_ptr[g], rp1 = row_ptr[g + 1];
    const float adv = ad_[g];

    float den = 0.f;
    float4 acc = make_float4(0.f, 0.f, 0.f, 0.f);
    int i = rp0;
    for (; i + 2 <= rp1; i += 2) {
        int c0 = cols[i], c1 = cols[i + 1];
        float4 h0 = *(const float4*)(h + (size_t)c0 * 64 + l * 4);
        float4 h1 = *(const float4*)(h + (size_t)c1 * 64 + l * 4);
        float lg0 = as_[c0] + adv; lg0 = (lg0 >= 0.f) ? lg0 : 0.2f * lg0;
        float lg1 = as_[c1] + adv; lg1 = (lg1 >= 0.f) ? lg1 : 0.2f * lg1;
        float e0 = __expf(lg0), e1 = __expf(lg1);
        den += e0 + e1;
        acc.x = fmaf(e0, h0.x, fmaf(e1, h1.x, acc.x));
        acc.y = fmaf(e0, h0.y, fmaf(e1, h1.y, acc.y));
        acc.z = fmaf(e0, h0.z, fmaf(e1, h1.z, acc.z));
        acc.w = fmaf(e0, h0.w, fmaf(e1, h1.w, acc.w));
    }
    if (i < rp1) {
        int c = cols[i];
        float4 hv = *(const float4*)(h + (size_t)c * 64 + l * 4);
        float lg = as_[c] + adv; lg = (lg >= 0.f) ? lg : 0.2f * lg;
        float ex = __expf(lg);
        den += ex;
        acc.x = fmaf(ex, hv.x, acc.x);
        acc.y = fmaf(ex, hv.y, acc.y);
        acc.z = fmaf(ex, hv.z, acc.z);
        acc.w = fmaf(ex, hv.w, acc.w);
    }
    float inv = 1.f / (den + 1e-16f);
    float4 o;
    o.x = acc.x * inv + bias[l * 4 + 0];
    o.y = acc.y * inv + bias[l * 4 + 1];
    o.z = acc.z * inv + bias[l * 4 + 2];
    o.w = acc.w * inv + bias[l * 4 + 3];
    if (RELU) {
        o.x = fmaxf(o.x, 0.f); o.y = fmaxf(o.y, 0.f);
        o.z = fmaxf(o.z, 0.f); o.w = fmaxf(o.w, 0.f);
    }
    *(float4*)(out + (size_t)g * 64 + l * 4) = o;
}

// Final edge MLP: out[e] = relu(Ps[s] + Pd[d]) . Wm2 + bm2, 8 lanes/edge.
__global__ __launch_bounds__(256) void edge_mlp(
    const int* __restrict__ ei, const float* __restrict__ ps,
    const float* __restrict__ pd, const float* __restrict__ Wm2,
    const float* __restrict__ bm2, float* __restrict__ out, int E)
{
    int tid = blockIdx.x * 256 + threadIdx.x;
    int e = tid >> 3;
    int l = tid & 7;
    if (e >= E) return;
    int s = ei[e], d = ei[E + e];
    float4 a = *(const float4*)(ps + (size_t)s * 32 + l * 4);
    float4 b = *(const float4*)(pd + (size_t)d * 32 + l * 4);
    float4 w = *(const float4*)(Wm2 + l * 4);
    float p = fmaxf(a.x + b.x, 0.f) * w.x + fmaxf(a.y + b.y, 0.f) * w.y
            + fmaxf(a.z + b.z, 0.f) * w.z + fmaxf(a.w + b.w, 0.f) * w.w;
    p += __shfl_xor(p, 4);
    p += __shfl_xor(p, 2);
    p += __shfl_xor(p, 1);
    if (l == 0) out[e] = p + bm2[0];
}

extern "C" void kernel_launch(void* const* d_in, const int* in_sizes, int n_in,
                              void* d_out, int out_size, void* d_ws, size_t ws_size,
                              hipStream_t stream)
{
    const float* x   = (const float*)d_in[0];
    const int*   ei  = (const int*)d_in[1];
    const float* W0  = (const float*)d_in[2];
    const float* b0  = (const float*)d_in[3];
    const float* W1  = (const float*)d_in[4];
    const float* as1 = (const float*)d_in[5];
    const float* ad1 = (const float*)d_in[6];
    const float* b1  = (const float*)d_in[7];
    const float* W2  = (const float*)d_in[8];
    const float* as2 = (const float*)d_in[9];
    const float* ad2 = (const float*)d_in[10];
    const float* b2  = (const float*)d_in[11];
    const float* W3  = (const float*)d_in[12];
    const float* as3 = (const float*)d_in[13];
    const float* ad3 = (const float*)d_in[14];
    const float* b3  = (const float*)d_in[15];
    const float* Wm1 = (const float*)d_in[16];
    const float* bm1 = (const float*)d_in[17];
    const float* Wm2 = (const float*)d_in[18];
    const float* bm2 = (const float*)d_in[19];
    float* out = (float*)d_out;

    const int N = in_sizes[0] / 128;
    const int E = in_sizes[1] / 2;
    const int Etot = E + N;

    // Workspace layout (persistent)
    float* ws = (float*)d_ws;
    float* A       = ws;                        // N x 64
    float* B       = A + (size_t)N * 64;        // N x 64
    float* C       = B + (size_t)N * 64;        // N x 64
    float* alpha_s = C + (size_t)N * 64;        // N
    float* alpha_d = alpha_s + N;               // N
    int* row_ptr   = (int*)(alpha_d + N);       // N + 1
    int* cols      = row_ptr + N + 1;           // Etot
    int* bsums     = cols + Etot;               // 256

    // CSR-build scratch aliased onto A/B (free until first GEMM)
    uint2* staged  = (uint2*)A;                 // Etot * 8B  (<= N*64*4B)
    const int nsb  = (Etot + SORT_EPB - 1) / SORT_EPB;
    const int nb   = (N + (1 << BUCKET_SHIFT) - 1) >> BUCKET_SHIFT;
    const int hlen = nb * nsb;
    int* hist      = (int*)B;                   // hlen
    int* hist_scan = hist + hlen;               // hlen

    const int nScanBlocks = (hlen + SCAN_CHUNK - 1) / SCAN_CHUNK;
    const int gNode64 = (N + 63) / 64;
    const int gGather = (N + 15) / 16;
    const int gMlp    = (E * 8 + 255) / 256;

    // ---- Build CSR by dst (edge set identical for all 3 layers) ----
    sort_hist<<<nsb, 256, 0, stream>>>(ei, hist, E, Etot, nb, nsb);
    scan_partial<<<nScanBlocks, 256, 0, stream>>>(hist, bsums, hlen);
    scan_bsums<<<1, 256, 0, stream>>>(bsums, nScanBlocks);
    scan_final_g<<<nScanBlocks, 256, 0, stream>>>(hist, bsums, hist_scan, hlen);
    sort_scatter<<<nsb, 256, 0, stream>>>(ei, hist_scan, staged, E, Etot, nb, nsb);
    bucket_fill<<<nb, 256, 0, stream>>>(staged, hist_scan, row_ptr, cols, N, Etot, nb, nsb);

    // h0 = x @ W0 + b0  -> A (N x 32)   [staged dead from here on]
    gemm_kernel<128, 32, false, false><<<gNode64, 256, 0, stream>>>(
        x, W0, b0, A, nullptr, nullptr, nullptr, nullptr, N);

    // ---- GAT layer 1: in A(32) -> h B(64) -> out C ----
    gemm_kernel<32, 64, false, true><<<gNode64, 256, 0, stream>>>(
        A, W1, nullptr, B, as1, ad1, alpha_s, alpha_d, N);
    gat_gather<true><<<gGather, 256, 0, stream>>>(
        row_ptr, cols, B, alpha_s, alpha_d, b1, C, N);

    // ---- GAT layer 2: in C -> h B -> out A ----
    gemm_kernel<64, 64, false, true><<<gNode64, 256, 0, stream>>>(
        C, W2, nullptr, B, as2, ad2, alpha_s, alpha_d, N);
    gat_gather<true><<<gGather, 256, 0, stream>>>(
        row_ptr, cols, B, alpha_s, alpha_d, b2, A, N);

    // ---- GAT layer 3: in A -> h B -> out C (no relu) ----
    gemm_kernel<64, 64, false, true><<<gNode64, 256, 0, stream>>>(
        A, W3, nullptr, B, as3, ad3, alpha_s, alpha_d, N);
    gat_gather<false><<<gGather, 256, 0, stream>>>(
        row_ptr, cols, B, alpha_s, alpha_d, b3, C, N);

    // ---- Final MLP, factorized over nodes (fused dual GEMM) ----
    float* Psrc = A;
    float* Pdst = A + (size_t)N * 32;
    gemm_dual<<<gNode64, 256, 0, stream>>>(C, Wm1, bm1, Psrc, Pdst, N);

    edge_mlp<<<gMlp, 256, 0, stream>>>(ei, Psrc, Pdst, Wm2, bm2, out, E);
}

// Round 10
// 561.393 us; speedup vs baseline: 3.6887x; 1.1700x over previous
//
#include <hip/hip_runtime.h>
#include <hip/hip_bf16.h>
#include <math.h>

// ---------------------------------------------------------------------------
// GNN: lin(128->32) -> 3x GATConv(heads=1, self-loops) -> edge MLP
// R1: CSR-by-dst built once; per-layer fused gather (no atomics in hot path).
// R3: multi-block hierarchical scan.
// R4: bucketed counting-sort CSR build; fused final dual GEMM.
// R5: gemm K-chunked + float4 staging; gat_gather single-pass (no max-shift).
// R7: coalesced LDS-staged GEMM epilogue. rocprof showed gemm<32,64> writing
//     183MB for a 26MB payload (7x amplification from scalar interleaved
//     stores, 64 lanes x 4B into 64 distinct lines per instruction). Now acc
//     is staged to LDS (reusing sW/sX space, +1 pad = conflict-free) and
//     stored as dense float4 (1KB contiguous per wave = full-line writes).
// R8, R9: identical resubmits (GPUAcquisitionTimeout — no data).
// ---------------------------------------------------------------------------

constexpr int SCAN_CHUNK   = 2048;   // elements per scan block (256 thr x 8)
constexpr int SORT_EPB     = 16384;  // edges per sort block
constexpr int BUCKET_SHIFT = 8;      // 256 dsts per bucket
constexpr int MAX_BUCKETS  = 1024;   // supports N <= 262144

// Tiled GEMM: out[n x M] = in[n x K] @ W[K x M] (+bias) (+relu)
// K processed in 64-wide chunks; X staged via float4 loads; coalesced epilogue.
// Optionally computes per-node alpha_src = h . avec_s, alpha_dst = h . avec_d.
template<int K, int M, bool RELU, bool ALPHA>
__global__ __launch_bounds__(256) void gemm_kernel(
    const float* __restrict__ in, const float* __restrict__ W,
    const float* __restrict__ bias, float* __restrict__ out,
    const float* __restrict__ avec_s, const float* __restrict__ avec_d,
    float* __restrict__ alpha_s, float* __restrict__ alpha_d, int n)
{
    constexpr int KC  = (K > 64) ? 64 : K;    // k-chunk width
    constexpr int NKB = K / KC;
    constexpr int SZ_WX  = (K * M + 64 * (KC + 1)) * 4;
    constexpr int SZ_OUT = 64 * (M + 1) * 4;
    constexpr int SZ = (SZ_WX > SZ_OUT) ? SZ_WX : SZ_OUT;
    __shared__ __align__(16) char smem[SZ];
    float (*sW)[M]      = reinterpret_cast<float (*)[M]>(smem);
    float (*sX)[KC + 1] = reinterpret_cast<float (*)[KC + 1]>(smem + (size_t)K * M * 4);
    float (*sOut)[M + 1]= reinterpret_cast<float (*)[M + 1]>(smem);  // reused post-compute

    for (int i = threadIdx.x; i < K * M; i += 256)
        sW[i / M][i % M] = W[i];

    const int base = blockIdx.x * 64;
    const int r  = threadIdx.x & 63;
    const int cg = threadIdx.x >> 6;          // 0..3
    constexpr int CPT = M / 4;                // cols per thread
    const int c0 = cg * CPT;

    float acc[CPT];
    #pragma unroll
    for (int j = 0; j < CPT; ++j) acc[j] = 0.f;

    for (int kb = 0; kb < NKB; ++kb) {
        __syncthreads();   // guards sW (first iter) / prev chunk reads
        // stage 64 x KC chunk with float4 loads (16B/lane, coalesced)
        for (int i = threadIdx.x; i < 64 * KC / 4; i += 256) {
            int rr = i / (KC / 4), c4 = (i % (KC / 4)) * 4;
            int node = base + rr;
            float4 v = (node < n)
                ? *(const float4*)(in + (size_t)node * K + kb * KC + c4)
                : make_float4(0.f, 0.f, 0.f, 0.f);
            sX[rr][c4 + 0] = v.x; sX[rr][c4 + 1] = v.y;
            sX[rr][c4 + 2] = v.z; sX[rr][c4 + 3] = v.w;
        }
        __syncthreads();
        #pragma unroll 4
        for (int k = 0; k < KC; ++k) {
            float xv = sX[r][k];
            #pragma unroll
            for (int j = 0; j < CPT; ++j)
                acc[j] = fmaf(xv, sW[kb * KC + k][c0 + j], acc[j]);
        }
    }

    // bias/relu in registers; alpha dot-products before smem reuse
    #pragma unroll
    for (int j = 0; j < CPT; ++j) {
        float v = acc[j] + (bias ? bias[c0 + j] : 0.f);
        if (RELU) v = fmaxf(v, 0.f);
        acc[j] = v;
    }
    float ps = 0.f, pd = 0.f;
    if constexpr (ALPHA) {
        #pragma unroll
        for (int j = 0; j < CPT; ++j) {
            ps = fmaf(acc[j], avec_s[c0 + j], ps);
            pd = fmaf(acc[j], avec_d[c0 + j], pd);
        }
    }

    __syncthreads();   // all waves done with sW/sX -> safe to reuse as sOut
    #pragma unroll
    for (int j = 0; j < CPT; ++j)
        sOut[r][c0 + j] = acc[j];   // bank = (r + c0+j) % 32: conflict-free

    __shared__ float sAS[4][64];
    __shared__ float sAD[4][64];
    if constexpr (ALPHA) {
        sAS[cg][r] = ps;
        sAD[cg][r] = pd;
    }
    __syncthreads();

    // cooperative dense store: each wave writes 1KB contiguous
    const int rows = min(64, n - base);
    const int nf4 = rows * (M / 4);
    for (int t = threadIdx.x; t < nf4; t += 256) {
        int row = t / (M / 4), col = (t % (M / 4)) * 4;
        float4 v = make_float4(sOut[row][col], sOut[row][col + 1],
                               sOut[row][col + 2], sOut[row][col + 3]);
        *(float4*)(out + (size_t)(base + row) * M + col) = v;
    }

    if constexpr (ALPHA) {
        if (threadIdx.x < 64 && base + r < n) {
            alpha_s[base + r] = sAS[0][r] + sAS[1][r] + sAS[2][r] + sAS[3][r];
            alpha_d[base + r] = sAD[0][r] + sAD[1][r] + sAD[2][r] + sAD[3][r];
        }
    }
}

// Fused final GEMM: Psrc = in@Wm1[0:64]+bm1, Pdst = in@Wm1[64:128]. K=64.
// Coalesced LDS-staged epilogue (same rationale as gemm_kernel).
__global__ __launch_bounds__(256) void gemm_dual(
    const float* __restrict__ in, const float* __restrict__ Wm1,
    const float* __restrict__ bm1, float* __restrict__ ps,
    float* __restrict__ pd, int n)
{
    constexpr int SZ_WX  = (128 * 32 + 64 * 65) * 4;      // 33 KB
    constexpr int SZ_OUT = 2 * 64 * 33 * 4;               // 16.9 KB
    constexpr int SZ = (SZ_WX > SZ_OUT) ? SZ_WX : SZ_OUT;
    __shared__ __align__(16) char smem[SZ];
    float (*sW)[32] = reinterpret_cast<float (*)[32]>(smem);
    float (*sX)[65] = reinterpret_cast<float (*)[65]>(smem + 128 * 32 * 4);
    float (*sO1)[33] = reinterpret_cast<float (*)[33]>(smem);
    float (*sO2)[33] = reinterpret_cast<float (*)[33]>(smem + 64 * 33 * 4);

    for (int i = threadIdx.x; i < 128 * 32; i += 256)
        sW[i >> 5][i & 31] = Wm1[i];
    const int base = blockIdx.x * 64;
    for (int i = threadIdx.x; i < 64 * 16; i += 256) {
        int rr = i >> 4, c4 = (i & 15) * 4;
        int node = base + rr;
        float4 v = (node < n)
            ? *(const float4*)(in + (size_t)node * 64 + c4)
            : make_float4(0.f, 0.f, 0.f, 0.f);
        sX[rr][c4 + 0] = v.x; sX[rr][c4 + 1] = v.y;
        sX[rr][c4 + 2] = v.z; sX[rr][c4 + 3] = v.w;
    }
    __syncthreads();
    const int r  = threadIdx.x & 63;
    const int cg = threadIdx.x >> 6;
    const int c0 = cg * 8;
    float a1[8], a2[8];
    #pragma unroll
    for (int j = 0; j < 8; ++j) { a1[j] = 0.f; a2[j] = 0.f; }
    #pragma unroll 4
    for (int k = 0; k < 64; ++k) {
        float xv = sX[r][k];
        #pragma unroll
        for (int j = 0; j < 8; ++j) {
            a1[j] = fmaf(xv, sW[k][c0 + j], a1[j]);
            a2[j] = fmaf(xv, sW[64 + k][c0 + j], a2[j]);
        }
    }
    #pragma unroll
    for (int j = 0; j < 8; ++j) a1[j] += bm1[c0 + j];

    __syncthreads();   // reuse smem as sO1/sO2
    #pragma unroll
    for (int j = 0; j < 8; ++j) {
        sO1[r][c0 + j] = a1[j];
        sO2[r][c0 + j] = a2[j];
    }
    __syncthreads();

    const int rows = min(64, n - base);
    const int nf4 = rows * 8;    // 32 cols / 4
    for (int t = threadIdx.x; t < nf4; t += 256) {
        int row = t >> 3, col = (t & 7) * 4;
        float4 v1 = make_float4(sO1[row][col], sO1[row][col + 1],
                                sO1[row][col + 2], sO1[row][col + 3]);
        float4 v2 = make_float4(sO2[row][col], sO2[row][col + 1],
                                sO2[row][col + 2], sO2[row][col + 3]);
        *(float4*)(ps + (size_t)(base + row) * 32 + col) = v1;
        *(float4*)(pd + (size_t)(base + row) * 32 + col) = v2;
    }
}

// ---- CSR build via bucketed counting sort (bucket = dst >> BUCKET_SHIFT) ----

// S1: per-(bucket, block) histogram. hist layout: hist[k * nsb + b].
__global__ __launch_bounds__(256) void sort_hist(
    const int* __restrict__ ei, int* __restrict__ hist,
    int E, int etot, int nb, int nsb)
{
    __shared__ int h[MAX_BUCKETS];
    for (int i = threadIdx.x; i < nb; i += 256) h[i] = 0;
    __syncthreads();
    const int base = blockIdx.x * SORT_EPB;
    const int end  = min(base + SORT_EPB, etot);
    for (int i = base + threadIdx.x; i < end; i += 256) {
        int d = (i < E) ? ei[E + i] : (i - E);
        atomicAdd(&h[d >> BUCKET_SHIFT], 1);
    }
    __syncthreads();
    for (int k = threadIdx.x; k < nb; k += 256)
        hist[k * nsb + blockIdx.x] = h[k];
}

// Generic 3-phase exclusive scan (len <= 256 * SCAN_CHUNK)
__global__ __launch_bounds__(256) void scan_partial(
    const int* __restrict__ in, int* __restrict__ bsums, int len)
{
    const int base = blockIdx.x * SCAN_CHUNK + threadIdx.x * 8;
    int s = 0;
    #pragma unroll
    for (int j = 0; j < 8; ++j) {
        int i = base + j;
        if (i < len) s += in[i];
    }
    s += __shfl_xor(s, 1);  s += __shfl_xor(s, 2);
    s += __shfl_xor(s, 4);  s += __shfl_xor(s, 8);
    s += __shfl_xor(s, 16); s += __shfl_xor(s, 32);
    __shared__ int red[4];
    if ((threadIdx.x & 63) == 0) red[threadIdx.x >> 6] = s;
    __syncthreads();
    if (threadIdx.x == 0) bsums[blockIdx.x] = red[0] + red[1] + red[2] + red[3];
}

__global__ __launch_bounds__(256) void scan_bsums(int* __restrict__ bsums, int nbk)
{
    __shared__ int sh[256];
    const int t = threadIdx.x;
    sh[t] = (t < nbk) ? bsums[t] : 0;
    __syncthreads();
    for (int off = 1; off < 256; off <<= 1) {
        int v = (t >= off) ? sh[t - off] : 0;
        __syncthreads();
        sh[t] += v;
        __syncthreads();
    }
    if (t < nbk) bsums[t] = (t == 0) ? 0 : sh[t - 1];   // exclusive
}

__global__ __launch_bounds__(256) void scan_final_g(
    const int* __restrict__ in, const int* __restrict__ bsums,
    int* __restrict__ out, int len)
{
    __shared__ int tsum[256];
    const int t = threadIdx.x;
    const int base = blockIdx.x * SCAN_CHUNK + t * 8;
    int loc[8];
    int s = 0;
    #pragma unroll
    for (int j = 0; j < 8; ++j) {
        int i = base + j;
        loc[j] = (i < len) ? in[i] : 0;
        s += loc[j];
    }
    tsum[t] = s;
    __syncthreads();
    for (int off = 1; off < 256; off <<= 1) {
        int v = (t >= off) ? tsum[t - off] : 0;
        __syncthreads();
        tsum[t] += v;
        __syncthreads();
    }
    int off = bsums[blockIdx.x] + ((t == 0) ? 0 : tsum[t - 1]);
    #pragma unroll
    for (int j = 0; j < 8; ++j) {
        int i = base + j;
        if (i < len) { out[i] = off; off += loc[j]; }
    }
}

// S2: scatter (src,dst) pairs into bucket-sorted staging (dense runs).
__global__ __launch_bounds__(256) void sort_scatter(
    const int* __restrict__ ei, const int* __restrict__ hist_scan,
    uint2* __restrict__ staged, int E, int etot, int nb, int nsb)
{
    __shared__ int cur[MAX_BUCKETS];
    for (int k = threadIdx.x; k < nb; k += 256)
        cur[k] = hist_scan[k * nsb + blockIdx.x];
    __syncthreads();
    const int base = blockIdx.x * SORT_EPB;
    const int end  = min(base + SORT_EPB, etot);
    for (int i = base + threadIdx.x; i < end; i += 256) {
        int s, d;
        if (i < E) { s = ei[i]; d = ei[E + i]; }
        else       { s = d = i - E; }
        int pos = atomicAdd(&cur[d >> BUCKET_SHIFT], 1);
        staged[pos] = make_uint2((unsigned)s, (unsigned)d);
    }
}

// S3: per-bucket: LDS dst-count -> prefix -> row_ptr (dense write) -> fill cols.
__global__ __launch_bounds__(256) void bucket_fill(
    const uint2* __restrict__ staged, const int* __restrict__ hist_scan,
    int* __restrict__ row_ptr, int* __restrict__ cols,
    int n, int etot, int nb, int nsb)
{
    __shared__ int cnt[256], scn[256], cur[256];
    const int k = blockIdx.x;
    const int dbase = k << BUCKET_SHIFT;
    const int ndst = min(256, n - dbase);
    const int bs = hist_scan[k * nsb];
    const int be = (k + 1 < nb) ? hist_scan[(k + 1) * nsb] : etot;
    const int t = threadIdx.x;
    cnt[t] = 0;
    __syncthreads();
    for (int i = bs + t; i < be; i += 256)
        atomicAdd(&cnt[staged[i].y - dbase], 1);
    __syncthreads();
    scn[t] = cnt[t];
    __syncthreads();
    for (int off = 1; off < 256; off <<= 1) {
        int v = (t >= off) ? scn[t - off] : 0;
        __syncthreads();
        scn[t] += v;
        __syncthreads();
    }
    const int rp = bs + scn[t] - cnt[t];   // exclusive prefix
    if (t < ndst) row_ptr[dbase + t] = rp;
    cur[t] = rp;
    __syncthreads();
    for (int i = bs + t; i < be; i += 256) {
        uint2 e = staged[i];
        int pos = atomicAdd(&cur[e.y - dbase], 1);
        cols[pos] = (int)e.x;
    }
    if (k == nb - 1 && t == 0) row_ptr[n] = etot;
}

// ---- Fused GAT aggregation: softmax + weighted gather + bias(+relu) ----
// Single pass, no max-shift (logits bounded far below fp32 exp overflow; the
// shift cancels exactly in ex/den). 16 lanes per dst node, float4 cols.
template<bool RELU>
__global__ __launch_bounds__(256) void gat_gather(
    const int* __restrict__ row_ptr, const int* __restrict__ cols,
    const float* __restrict__ h, const float* __restrict__ as_,
    const float* __restrict__ ad_, const float* __restrict__ bias,
    float* __restrict__ out, int n)
{
    const int g = blockIdx.x * 16 + (threadIdx.x >> 4);   // dst node
    const int l = threadIdx.x & 15;
    if (g >= n) return;
    const int rp0 = row_ptr[g], rp1 = row_ptr[g + 1];
    const float adv = ad_[g];

    float den = 0.f;
    float4 acc = make_float4(0.f, 0.f, 0.f, 0.f);
    int i = rp0;
    for (; i + 2 <= rp1; i += 2) {
        int c0 = cols[i], c1 = cols[i + 1];
        float4 h0 = *(const float4*)(h + (size_t)c0 * 64 + l * 4);
        float4 h1 = *(const float4*)(h + (size_t)c1 * 64 + l * 4);
        float lg0 = as_[c0] + adv; lg0 = (lg0 >= 0.f) ? lg0 : 0.2f * lg0;
        float lg1 = as_[c1] + adv; lg1 = (lg1 >= 0.f) ? lg1 : 0.2f * lg1;
        float e0 = __expf(lg0), e1 = __expf(lg1);
        den += e0 + e1;
        acc.x = fmaf(e0, h0.x, fmaf(e1, h1.x, acc.x));
        acc.y = fmaf(e0, h0.y, fmaf(e1, h1.y, acc.y));
        acc.z = fmaf(e0, h0.z, fmaf(e1, h1.z, acc.z));
        acc.w = fmaf(e0, h0.w, fmaf(e1, h1.w, acc.w));
    }
    if (i < rp1) {
        int c = cols[i];
        float4 hv = *(const float4*)(h + (size_t)c * 64 + l * 4);
        float lg = as_[c] + adv; lg = (lg >= 0.f) ? lg : 0.2f * lg;
        float ex = __expf(lg);
        den += ex;
        acc.x = fmaf(ex, hv.x, acc.x);
        acc.y = fmaf(ex, hv.y, acc.y);
        acc.z = fmaf(ex, hv.z, acc.z);
        acc.w = fmaf(ex, hv.w, acc.w);
    }
    float inv = 1.f / (den + 1e-16f);
    float4 o;
    o.x = acc.x * inv + bias[l * 4 + 0];
    o.y = acc.y * inv + bias[l * 4 + 1];
    o.z = acc.z * inv + bias[l * 4 + 2];
    o.w = acc.w * inv + bias[l * 4 + 3];
    if (RELU) {
        o.x = fmaxf(o.x, 0.f); o.y = fmaxf(o.y, 0.f);
        o.z = fmaxf(o.z, 0.f); o.w = fmaxf(o.w, 0.f);
    }
    *(float4*)(out + (size_t)g * 64 + l * 4) = o;
}

// Final edge MLP: out[e] = relu(Ps[s] + Pd[d]) . Wm2 + bm2, 8 lanes/edge.
__global__ __launch_bounds__(256) void edge_mlp(
    const int* __restrict__ ei, const float* __restrict__ ps,
    const float* __restrict__ pd, const float* __restrict__ Wm2,
    const float* __restrict__ bm2, float* __restrict__ out, int E)
{
    int tid = blockIdx.x * 256 + threadIdx.x;
    int e = tid >> 3;
    int l = tid & 7;
    if (e >= E) return;
    int s = ei[e], d = ei[E + e];
    float4 a = *(const float4*)(ps + (size_t)s * 32 + l * 4);
    float4 b = *(const float4*)(pd + (size_t)d * 32 + l * 4);
    float4 w = *(const float4*)(Wm2 + l * 4);
    float p = fmaxf(a.x + b.x, 0.f) * w.x + fmaxf(a.y + b.y, 0.f) * w.y
            + fmaxf(a.z + b.z, 0.f) * w.z + fmaxf(a.w + b.w, 0.f) * w.w;
    p += __shfl_xor(p, 4);
    p += __shfl_xor(p, 2);
    p += __shfl_xor(p, 1);
    if (l == 0) out[e] = p + bm2[0];
}

extern "C" void kernel_launch(void* const* d_in, const int* in_sizes, int n_in,
                              void* d_out, int out_size, void* d_ws, size_t ws_size,
                              hipStream_t stream)
{
    const float* x   = (const float*)d_in[0];
    const int*   ei  = (const int*)d_in[1];
    const float* W0  = (const float*)d_in[2];
    const float* b0  = (const float*)d_in[3];
    const float* W1  = (const float*)d_in[4];
    const float* as1 = (const float*)d_in[5];
    const float* ad1 = (const float*)d_in[6];
    const float* b1  = (const float*)d_in[7];
    const float* W2  = (const float*)d_in[8];
    const float* as2 = (const float*)d_in[9];
    const float* ad2 = (const float*)d_in[10];
    const float* b2  = (const float*)d_in[11];
    const float* W3  = (const float*)d_in[12];
    const float* as3 = (const float*)d_in[13];
    const float* ad3 = (const float*)d_in[14];
    const float* b3  = (const float*)d_in[15];
    const float* Wm1 = (const float*)d_in[16];
    const float* bm1 = (const float*)d_in[17];
    const float* Wm2 = (const float*)d_in[18];
    const float* bm2 = (const float*)d_in[19];
    float* out = (float*)d_out;

    const int N = in_sizes[0] / 128;
    const int E = in_sizes[1] / 2;
    const int Etot = E + N;

    // Workspace layout (persistent)
    float* ws = (float*)d_ws;
    float* A       = ws;                        // N x 64
    float* B       = A + (size_t)N * 64;        // N x 64
    float* C       = B + (size_t)N * 64;        // N x 64
    float* alpha_s = C + (size_t)N * 64;        // N
    float* alpha_d = alpha_s + N;               // N
    int* row_ptr   = (int*)(alpha_d + N);       // N + 1
    int* cols      = row_ptr + N + 1;           // Etot
    int* bsums     = cols + Etot;               // 256

    // CSR-build scratch aliased onto A/B (free until first GEMM)
    uint2* staged  = (uint2*)A;                 // Etot * 8B  (<= N*64*4B)
    const int nsb  = (Etot + SORT_EPB - 1) / SORT_EPB;
    const int nb   = (N + (1 << BUCKET_SHIFT) - 1) >> BUCKET_SHIFT;
    const int hlen = nb * nsb;
    int* hist      = (int*)B;                   // hlen
    int* hist_scan = hist + hlen;               // hlen

    const int nScanBlocks = (hlen + SCAN_CHUNK - 1) / SCAN_CHUNK;
    const int gNode64 = (N + 63) / 64;
    const int gGather = (N + 15) / 16;
    const int gMlp    = (E * 8 + 255) / 256;

    // ---- Build CSR by dst (edge set identical for all 3 layers) ----
    sort_hist<<<nsb, 256, 0, stream>>>(ei, hist, E, Etot, nb, nsb);
    scan_partial<<<nScanBlocks, 256, 0, stream>>>(hist, bsums, hlen);
    scan_bsums<<<1, 256, 0, stream>>>(bsums, nScanBlocks);
    scan_final_g<<<nScanBlocks, 256, 0, stream>>>(hist, bsums, hist_scan, hlen);
    sort_scatter<<<nsb, 256, 0, stream>>>(ei, hist_scan, staged, E, Etot, nb, nsb);
    bucket_fill<<<nb, 256, 0, stream>>>(staged, hist_scan, row_ptr, cols, N, Etot, nb, nsb);

    // h0 = x @ W0 + b0  -> A (N x 32)   [staged dead from here on]
    gemm_kernel<128, 32, false, false><<<gNode64, 256, 0, stream>>>(
        x, W0, b0, A, nullptr, nullptr, nullptr, nullptr, N);

    // ---- GAT layer 1: in A(32) -> h B(64) -> out C ----
    gemm_kernel<32, 64, false, true><<<gNode64, 256, 0, stream>>>(
        A, W1, nullptr, B, as1, ad1, alpha_s, alpha_d, N);
    gat_gather<true><<<gGather, 256, 0, stream>>>(
        row_ptr, cols, B, alpha_s, alpha_d, b1, C, N);

    // ---- GAT layer 2: in C -> h B -> out A ----
    gemm_kernel<64, 64, false, true><<<gNode64, 256, 0, stream>>>(
        C, W2, nullptr, B, as2, ad2, alpha_s, alpha_d, N);
    gat_gather<true><<<gGather, 256, 0, stream>>>(
        row_ptr, cols, B, alpha_s, alpha_d, b2, A, N);

    // ---- GAT layer 3: in A -> h B -> out C (no relu) ----
    gemm_kernel<64, 64, false, true><<<gNode64, 256, 0, stream>>>(
        A, W3, nullptr, B, as3, ad3, alpha_s, alpha_d, N);
    gat_gather<false><<<gGather, 256, 0, stream>>>(
        row_ptr, cols, B, alpha_s, alpha_d, b3, C, N);

    // ---- Final MLP, factorized over nodes (fused dual GEMM) ----
    float* Psrc = A;
    float* Pdst = A + (size_t)N * 32;
    gemm_dual<<<gNode64, 256, 0, stream>>>(C, Wm1, bm1, Psrc, Pdst, N);

    edge_mlp<<<gMlp, 256, 0, stream>>>(ei, Psrc, Pdst, Wm2, bm2, out, E);
}

// Round 12
// 555.355 us; speedup vs baseline: 3.7288x; 1.0109x over previous
//
#include <hip/hip_runtime.h>
#include <hip/hip_bf16.h>
#include <math.h>

// ---------------------------------------------------------------------------
// GNN: lin(128->32) -> 3x GATConv(heads=1, self-loops) -> edge MLP
// R1: CSR-by-dst built once; per-layer fused gather (no atomics in hot path).
// R3: multi-block hierarchical scan.
// R4: bucketed counting-sort CSR build; fused final dual GEMM.
// R5: gemm K-chunked + float4 staging; gat_gather single-pass (no max-shift).
// R7: coalesced LDS-staged GEMM epilogue (fixed 7x write amplification).
// R10: gat_gather unroll x4 (4 h-row loads in flight per 16-lane group —
//      theory: latency-bound on L3 random reads, VALUBusy 25%/HBM 44%);
//      edge_mlp 2 edges per group + float2 output write.
// R11: identical resubmit (R10 bench was GPUAcquisitionTimeout — no data).
// ---------------------------------------------------------------------------

constexpr int SCAN_CHUNK   = 2048;   // elements per scan block (256 thr x 8)
constexpr int SORT_EPB     = 16384;  // edges per sort block
constexpr int BUCKET_SHIFT = 8;      // 256 dsts per bucket
constexpr int MAX_BUCKETS  = 1024;   // supports N <= 262144

// Tiled GEMM: out[n x M] = in[n x K] @ W[K x M] (+bias) (+relu)
// K processed in 64-wide chunks; X staged via float4 loads; coalesced epilogue.
// Optionally computes per-node alpha_src = h . avec_s, alpha_dst = h . avec_d.
template<int K, int M, bool RELU, bool ALPHA>
__global__ __launch_bounds__(256) void gemm_kernel(
    const float* __restrict__ in, const float* __restrict__ W,
    const float* __restrict__ bias, float* __restrict__ out,
    const float* __restrict__ avec_s, const float* __restrict__ avec_d,
    float* __restrict__ alpha_s, float* __restrict__ alpha_d, int n)
{
    constexpr int KC  = (K > 64) ? 64 : K;    // k-chunk width
    constexpr int NKB = K / KC;
    constexpr int SZ_WX  = (K * M + 64 * (KC + 1)) * 4;
    constexpr int SZ_OUT = 64 * (M + 1) * 4;
    constexpr int SZ = (SZ_WX > SZ_OUT) ? SZ_WX : SZ_OUT;
    __shared__ __align__(16) char smem[SZ];
    float (*sW)[M]      = reinterpret_cast<float (*)[M]>(smem);
    float (*sX)[KC + 1] = reinterpret_cast<float (*)[KC + 1]>(smem + (size_t)K * M * 4);
    float (*sOut)[M + 1]= reinterpret_cast<float (*)[M + 1]>(smem);  // reused post-compute

    for (int i = threadIdx.x; i < K * M; i += 256)
        sW[i / M][i % M] = W[i];

    const int base = blockIdx.x * 64;
    const int r  = threadIdx.x & 63;
    const int cg = threadIdx.x >> 6;          // 0..3
    constexpr int CPT = M / 4;                // cols per thread
    const int c0 = cg * CPT;

    float acc[CPT];
    #pragma unroll
    for (int j = 0; j < CPT; ++j) acc[j] = 0.f;

    for (int kb = 0; kb < NKB; ++kb) {
        __syncthreads();   // guards sW (first iter) / prev chunk reads
        // stage 64 x KC chunk with float4 loads (16B/lane, coalesced)
        for (int i = threadIdx.x; i < 64 * KC / 4; i += 256) {
            int rr = i / (KC / 4), c4 = (i % (KC / 4)) * 4;
            int node = base + rr;
            float4 v = (node < n)
                ? *(const float4*)(in + (size_t)node * K + kb * KC + c4)
                : make_float4(0.f, 0.f, 0.f, 0.f);
            sX[rr][c4 + 0] = v.x; sX[rr][c4 + 1] = v.y;
            sX[rr][c4 + 2] = v.z; sX[rr][c4 + 3] = v.w;
        }
        __syncthreads();
        #pragma unroll 4
        for (int k = 0; k < KC; ++k) {
            float xv = sX[r][k];
            #pragma unroll
            for (int j = 0; j < CPT; ++j)
                acc[j] = fmaf(xv, sW[kb * KC + k][c0 + j], acc[j]);
        }
    }

    // bias/relu in registers; alpha dot-products before smem reuse
    #pragma unroll
    for (int j = 0; j < CPT; ++j) {
        float v = acc[j] + (bias ? bias[c0 + j] : 0.f);
        if (RELU) v = fmaxf(v, 0.f);
        acc[j] = v;
    }
    float ps = 0.f, pd = 0.f;
    if constexpr (ALPHA) {
        #pragma unroll
        for (int j = 0; j < CPT; ++j) {
            ps = fmaf(acc[j], avec_s[c0 + j], ps);
            pd = fmaf(acc[j], avec_d[c0 + j], pd);
        }
    }

    __syncthreads();   // all waves done with sW/sX -> safe to reuse as sOut
    #pragma unroll
    for (int j = 0; j < CPT; ++j)
        sOut[r][c0 + j] = acc[j];   // bank = (r + c0+j) % 32: conflict-free

    __shared__ float sAS[4][64];
    __shared__ float sAD[4][64];
    if constexpr (ALPHA) {
        sAS[cg][r] = ps;
        sAD[cg][r] = pd;
    }
    __syncthreads();

    // cooperative dense store: each wave writes 1KB contiguous
    const int rows = min(64, n - base);
    const int nf4 = rows * (M / 4);
    for (int t = threadIdx.x; t < nf4; t += 256) {
        int row = t / (M / 4), col = (t % (M / 4)) * 4;
        float4 v = make_float4(sOut[row][col], sOut[row][col + 1],
                               sOut[row][col + 2], sOut[row][col + 3]);
        *(float4*)(out + (size_t)(base + row) * M + col) = v;
    }

    if constexpr (ALPHA) {
        if (threadIdx.x < 64 && base + r < n) {
            alpha_s[base + r] = sAS[0][r] + sAS[1][r] + sAS[2][r] + sAS[3][r];
            alpha_d[base + r] = sAD[0][r] + sAD[1][r] + sAD[2][r] + sAD[3][r];
        }
    }
}

// Fused final GEMM: Psrc = in@Wm1[0:64]+bm1, Pdst = in@Wm1[64:128]. K=64.
// Coalesced LDS-staged epilogue (same rationale as gemm_kernel).
__global__ __launch_bounds__(256) void gemm_dual(
    const float* __restrict__ in, const float* __restrict__ Wm1,
    const float* __restrict__ bm1, float* __restrict__ ps,
    float* __restrict__ pd, int n)
{
    constexpr int SZ_WX  = (128 * 32 + 64 * 65) * 4;      // 33 KB
    constexpr int SZ_OUT = 2 * 64 * 33 * 4;               // 16.9 KB
    constexpr int SZ = (SZ_WX > SZ_OUT) ? SZ_WX : SZ_OUT;
    __shared__ __align__(16) char smem[SZ];
    float (*sW)[32] = reinterpret_cast<float (*)[32]>(smem);
    float (*sX)[65] = reinterpret_cast<float (*)[65]>(smem + 128 * 32 * 4);
    float (*sO1)[33] = reinterpret_cast<float (*)[33]>(smem);
    float (*sO2)[33] = reinterpret_cast<float (*)[33]>(smem + 64 * 33 * 4);

    for (int i = threadIdx.x; i < 128 * 32; i += 256)
        sW[i >> 5][i & 31] = Wm1[i];
    const int base = blockIdx.x * 64;
    for (int i = threadIdx.x; i < 64 * 16; i += 256) {
        int rr = i >> 4, c4 = (i & 15) * 4;
        int node = base + rr;
        float4 v = (node < n)
            ? *(const float4*)(in + (size_t)node * 64 + c4)
            : make_float4(0.f, 0.f, 0.f, 0.f);
        sX[rr][c4 + 0] = v.x; sX[rr][c4 + 1] = v.y;
        sX[rr][c4 + 2] = v.z; sX[rr][c4 + 3] = v.w;
    }
    __syncthreads();
    const int r  = threadIdx.x & 63;
    const int cg = threadIdx.x >> 6;
    const int c0 = cg * 8;
    float a1[8], a2[8];
    #pragma unroll
    for (int j = 0; j < 8; ++j) { a1[j] = 0.f; a2[j] = 0.f; }
    #pragma unroll 4
    for (int k = 0; k < 64; ++k) {
        float xv = sX[r][k];
        #pragma unroll
        for (int j = 0; j < 8; ++j) {
            a1[j] = fmaf(xv, sW[k][c0 + j], a1[j]);
            a2[j] = fmaf(xv, sW[64 + k][c0 + j], a2[j]);
        }
    }
    #pragma unroll
    for (int j = 0; j < 8; ++j) a1[j] += bm1[c0 + j];

    __syncthreads();   // reuse smem as sO1/sO2
    #pragma unroll
    for (int j = 0; j < 8; ++j) {
        sO1[r][c0 + j] = a1[j];
        sO2[r][c0 + j] = a2[j];
    }
    __syncthreads();

    const int rows = min(64, n - base);
    const int nf4 = rows * 8;    // 32 cols / 4
    for (int t = threadIdx.x; t < nf4; t += 256) {
        int row = t >> 3, col = (t & 7) * 4;
        float4 v1 = make_float4(sO1[row][col], sO1[row][col + 1],
                                sO1[row][col + 2], sO1[row][col + 3]);
        float4 v2 = make_float4(sO2[row][col], sO2[row][col + 1],
                                sO2[row][col + 2], sO2[row][col + 3]);
        *(float4*)(ps + (size_t)(base + row) * 32 + col) = v1;
        *(float4*)(pd + (size_t)(base + row) * 32 + col) = v2;
    }
}

// ---- CSR build via bucketed counting sort (bucket = dst >> BUCKET_SHIFT) ----

// S1: per-(bucket, block) histogram. hist layout: hist[k * nsb + b].
__global__ __launch_bounds__(256) void sort_hist(
    const int* __restrict__ ei, int* __restrict__ hist,
    int E, int etot, int nb, int nsb)
{
    __shared__ int h[MAX_BUCKETS];
    for (int i = threadIdx.x; i < nb; i += 256) h[i] = 0;
    __syncthreads();
    const int base = blockIdx.x * SORT_EPB;
    const int end  = min(base + SORT_EPB, etot);
    for (int i = base + threadIdx.x; i < end; i += 256) {
        int d = (i < E) ? ei[E + i] : (i - E);
        atomicAdd(&h[d >> BUCKET_SHIFT], 1);
    }
    __syncthreads();
    for (int k = threadIdx.x; k < nb; k += 256)
        hist[k * nsb + blockIdx.x] = h[k];
}

// Generic 3-phase exclusive scan (len <= 256 * SCAN_CHUNK)
__global__ __launch_bounds__(256) void scan_partial(
    const int* __restrict__ in, int* __restrict__ bsums, int len)
{
    const int base = blockIdx.x * SCAN_CHUNK + threadIdx.x * 8;
    int s = 0;
    #pragma unroll
    for (int j = 0; j < 8; ++j) {
        int i = base + j;
        if (i < len) s += in[i];
    }
    s += __shfl_xor(s, 1);  s += __shfl_xor(s, 2);
    s += __shfl_xor(s, 4);  s += __shfl_xor(s, 8);
    s += __shfl_xor(s, 16); s += __shfl_xor(s, 32);
    __shared__ int red[4];
    if ((threadIdx.x & 63) == 0) red[threadIdx.x >> 6] = s;
    __syncthreads();
    if (threadIdx.x == 0) bsums[blockIdx.x] = red[0] + red[1] + red[2] + red[3];
}

__global__ __launch_bounds__(256) void scan_bsums(int* __restrict__ bsums, int nbk)
{
    __shared__ int sh[256];
    const int t = threadIdx.x;
    sh[t] = (t < nbk) ? bsums[t] : 0;
    __syncthreads();
    for (int off = 1; off < 256; off <<= 1) {
        int v = (t >= off) ? sh[t - off] : 0;
        __syncthreads();
        sh[t] += v;
        __syncthreads();
    }
    if (t < nbk) bsums[t] = (t == 0) ? 0 : sh[t - 1];   // exclusive
}

__global__ __launch_bounds__(256) void scan_final_g(
    const int* __restrict__ in, const int* __restrict__ bsums,
    int* __restrict__ out, int len)
{
    __shared__ int tsum[256];
    const int t = threadIdx.x;
    const int base = blockIdx.x * SCAN_CHUNK + t * 8;
    int loc[8];
    int s = 0;
    #pragma unroll
    for (int j = 0; j < 8; ++j) {
        int i = base + j;
        loc[j] = (i < len) ? in[i] : 0;
        s += loc[j];
    }
    tsum[t] = s;
    __syncthreads();
    for (int off = 1; off < 256; off <<= 1) {
        int v = (t >= off) ? tsum[t - off] : 0;
        __syncthreads();
        tsum[t] += v;
        __syncthreads();
    }
    int off = bsums[blockIdx.x] + ((t == 0) ? 0 : tsum[t - 1]);
    #pragma unroll
    for (int j = 0; j < 8; ++j) {
        int i = base + j;
        if (i < len) { out[i] = off; off += loc[j]; }
    }
}

// S2: scatter (src,dst) pairs into bucket-sorted staging (dense runs).
__global__ __launch_bounds__(256) void sort_scatter(
    const int* __restrict__ ei, const int* __restrict__ hist_scan,
    uint2* __restrict__ staged, int E, int etot, int nb, int nsb)
{
    __shared__ int cur[MAX_BUCKETS];
    for (int k = threadIdx.x; k < nb; k += 256)
        cur[k] = hist_scan[k * nsb + blockIdx.x];
    __syncthreads();
    const int base = blockIdx.x * SORT_EPB;
    const int end  = min(base + SORT_EPB, etot);
    for (int i = base + threadIdx.x; i < end; i += 256) {
        int s, d;
        if (i < E) { s = ei[i]; d = ei[E + i]; }
        else       { s = d = i - E; }
        int pos = atomicAdd(&cur[d >> BUCKET_SHIFT], 1);
        staged[pos] = make_uint2((unsigned)s, (unsigned)d);
    }
}

// S3: per-bucket: LDS dst-count -> prefix -> row_ptr (dense write) -> fill cols.
__global__ __launch_bounds__(256) void bucket_fill(
    const uint2* __restrict__ staged, const int* __restrict__ hist_scan,
    int* __restrict__ row_ptr, int* __restrict__ cols,
    int n, int etot, int nb, int nsb)
{
    __shared__ int cnt[256], scn[256], cur[256];
    const int k = blockIdx.x;
    const int dbase = k << BUCKET_SHIFT;
    const int ndst = min(256, n - dbase);
    const int bs = hist_scan[k * nsb];
    const int be = (k + 1 < nb) ? hist_scan[(k + 1) * nsb] : etot;
    const int t = threadIdx.x;
    cnt[t] = 0;
    __syncthreads();
    for (int i = bs + t; i < be; i += 256)
        atomicAdd(&cnt[staged[i].y - dbase], 1);
    __syncthreads();
    scn[t] = cnt[t];
    __syncthreads();
    for (int off = 1; off < 256; off <<= 1) {
        int v = (t >= off) ? scn[t - off] : 0;
        __syncthreads();
        scn[t] += v;
        __syncthreads();
    }
    const int rp = bs + scn[t] - cnt[t];   // exclusive prefix
    if (t < ndst) row_ptr[dbase + t] = rp;
    cur[t] = rp;
    __syncthreads();
    for (int i = bs + t; i < be; i += 256) {
        uint2 e = staged[i];
        int pos = atomicAdd(&cur[e.y - dbase], 1);
        cols[pos] = (int)e.x;
    }
    if (k == nb - 1 && t == 0) row_ptr[n] = etot;
}

// ---- Fused GAT aggregation: softmax + weighted gather + bias(+relu) ----
// Single pass, no max-shift (logits bounded far below fp32 exp overflow; the
// shift cancels exactly in ex/den). 16 lanes per dst node, float4 cols.
// 4x unrolled: four independent h-row loads issued before dependent exp math.
template<bool RELU>
__global__ __launch_bounds__(256) void gat_gather(
    const int* __restrict__ row_ptr, const int* __restrict__ cols,
    const float* __restrict__ h, const float* __restrict__ as_,
    const float* __restrict__ ad_, const float* __restrict__ bias,
    float* __restrict__ out, int n)
{
    const int g = blockIdx.x * 16 + (threadIdx.x >> 4);   // dst node
    const int l = threadIdx.x & 15;
    if (g >= n) return;
    const int rp0 = row_ptr[g], rp1 = row_ptr[g + 1];
    const float adv = ad_[g];

    float den = 0.f;
    float4 acc = make_float4(0.f, 0.f, 0.f, 0.f);
    int i = rp0;
    for (; i + 4 <= rp1; i += 4) {
        int c0 = cols[i], c1 = cols[i + 1], c2 = cols[i + 2], c3 = cols[i + 3];
        float4 h0 = *(const float4*)(h + (size_t)c0 * 64 + l * 4);
        float4 h1 = *(const float4*)(h + (size_t)c1 * 64 + l * 4);
        float4 h2 = *(const float4*)(h + (size_t)c2 * 64 + l * 4);
        float4 h3 = *(const float4*)(h + (size_t)c3 * 64 + l * 4);
        float a0 = as_[c0], a1 = as_[c1], a2 = as_[c2], a3 = as_[c3];
        float lg0 = a0 + adv; lg0 = (lg0 >= 0.f) ? lg0 : 0.2f * lg0;
        float lg1 = a1 + adv; lg1 = (lg1 >= 0.f) ? lg1 : 0.2f * lg1;
        float lg2 = a2 + adv; lg2 = (lg2 >= 0.f) ? lg2 : 0.2f * lg2;
        float lg3 = a3 + adv; lg3 = (lg3 >= 0.f) ? lg3 : 0.2f * lg3;
        float e0 = __expf(lg0), e1 = __expf(lg1);
        float e2 = __expf(lg2), e3 = __expf(lg3);
        den += (e0 + e1) + (e2 + e3);
        acc.x = fmaf(e0, h0.x, fmaf(e1, h1.x, fmaf(e2, h2.x, fmaf(e3, h3.x, acc.x))));
        acc.y = fmaf(e0, h0.y, fmaf(e1, h1.y, fmaf(e2, h2.y, fmaf(e3, h3.y, acc.y))));
        acc.z = fmaf(e0, h0.z, fmaf(e1, h1.z, fmaf(e2, h2.z, fmaf(e3, h3.z, acc.z))));
        acc.w = fmaf(e0, h0.w, fmaf(e1, h1.w, fmaf(e2, h2.w, fmaf(e3, h3.w, acc.w))));
    }
    for (; i < rp1; ++i) {
        int c = cols[i];
        float4 hv = *(const float4*)(h + (size_t)c * 64 + l * 4);
        float lg = as_[c] + adv; lg = (lg >= 0.f) ? lg : 0.2f * lg;
        float ex = __expf(lg);
        den += ex;
        acc.x = fmaf(ex, hv.x, acc.x);
        acc.y = fmaf(ex, hv.y, acc.y);
        acc.z = fmaf(ex, hv.z, acc.z);
        acc.w = fmaf(ex, hv.w, acc.w);
    }
    float inv = 1.f / (den + 1e-16f);
    float4 o;
    o.x = acc.x * inv + bias[l * 4 + 0];
    o.y = acc.y * inv + bias[l * 4 + 1];
    o.z = acc.z * inv + bias[l * 4 + 2];
    o.w = acc.w * inv + bias[l * 4 + 3];
    if (RELU) {
        o.x = fmaxf(o.x, 0.f); o.y = fmaxf(o.y, 0.f);
        o.z = fmaxf(o.z, 0.f); o.w = fmaxf(o.w, 0.f);
    }
    *(float4*)(out + (size_t)g * 64 + l * 4) = o;
}

// Final edge MLP: out[e] = relu(Ps[s] + Pd[d]) . Wm2 + bm2.
// 8 lanes per edge, 2 consecutive edges per group (both load pairs in flight;
// lane 0 writes a coalesced float2).
__global__ __launch_bounds__(256) void edge_mlp(
    const int* __restrict__ ei, const float* __restrict__ ps,
    const float* __restrict__ pd, const float* __restrict__ Wm2,
    const float* __restrict__ bm2, float* __restrict__ out, int E)
{
    int tid = blockIdx.x * 256 + threadIdx.x;
    int k = tid >> 3;
    int l = tid & 7;
    int e0 = 2 * k, e1 = 2 * k + 1;
    if (e0 >= E) return;
    float4 w = *(const float4*)(Wm2 + l * 4);
    int s0 = ei[e0], d0 = ei[E + e0];
    float4 a0 = *(const float4*)(ps + (size_t)s0 * 32 + l * 4);
    float4 b0 = *(const float4*)(pd + (size_t)d0 * 32 + l * 4);
    bool has1 = (e1 < E);
    int s1 = has1 ? ei[e1] : s0, d1 = has1 ? ei[E + e1] : d0;
    float4 a1 = *(const float4*)(ps + (size_t)s1 * 32 + l * 4);
    float4 b1 = *(const float4*)(pd + (size_t)d1 * 32 + l * 4);

    float p0 = fmaxf(a0.x + b0.x, 0.f) * w.x + fmaxf(a0.y + b0.y, 0.f) * w.y
             + fmaxf(a0.z + b0.z, 0.f) * w.z + fmaxf(a0.w + b0.w, 0.f) * w.w;
    float p1 = fmaxf(a1.x + b1.x, 0.f) * w.x + fmaxf(a1.y + b1.y, 0.f) * w.y
             + fmaxf(a1.z + b1.z, 0.f) * w.z + fmaxf(a1.w + b1.w, 0.f) * w.w;
    p0 += __shfl_xor(p0, 4); p0 += __shfl_xor(p0, 2); p0 += __shfl_xor(p0, 1);
    p1 += __shfl_xor(p1, 4); p1 += __shfl_xor(p1, 2); p1 += __shfl_xor(p1, 1);
    if (l == 0) {
        float bb = bm2[0];
        if (has1) *(float2*)(out + e0) = make_float2(p0 + bb, p1 + bb);
        else      out[e0] = p0 + bb;
    }
}

extern "C" void kernel_launch(void* const* d_in, const int* in_sizes, int n_in,
                              void* d_out, int out_size, void* d_ws, size_t ws_size,
                              hipStream_t stream)
{
    const float* x   = (const float*)d_in[0];
    const int*   ei  = (const int*)d_in[1];
    const float* W0  = (const float*)d_in[2];
    const float* b0  = (const float*)d_in[3];
    const float* W1  = (const float*)d_in[4];
    const float* as1 = (const float*)d_in[5];
    const float* ad1 = (const float*)d_in[6];
    const float* b1  = (const float*)d_in[7];
    const float* W2  = (const float*)d_in[8];
    const float* as2 = (const float*)d_in[9];
    const float* ad2 = (const float*)d_in[10];
    const float* b2  = (const float*)d_in[11];
    const float* W3  = (const float*)d_in[12];
    const float* as3 = (const float*)d_in[13];
    const float* ad3 = (const float*)d_in[14];
    const float* b3  = (const float*)d_in[15];
    const float* Wm1 = (const float*)d_in[16];
    const float* bm1 = (const float*)d_in[17];
    const float* Wm2 = (const float*)d_in[18];
    const float* bm2 = (const float*)d_in[19];
    float* out = (float*)d_out;

    const int N = in_sizes[0] / 128;
    const int E = in_sizes[1] / 2;
    const int Etot = E + N;

    // Workspace layout (persistent)
    float* ws = (float*)d_ws;
    float* A       = ws;                        // N x 64
    float* B       = A + (size_t)N * 64;        // N x 64
    float* C       = B + (size_t)N * 64;        // N x 64
    float* alpha_s = C + (size_t)N * 64;        // N
    float* alpha_d = alpha_s + N;               // N
    int* row_ptr   = (int*)(alpha_d + N);       // N + 1
    int* cols      = row_ptr + N + 1;           // Etot
    int* bsums     = cols + Etot;               // 256

    // CSR-build scratch aliased onto A/B (free until first GEMM)
    uint2* staged  = (uint2*)A;                 // Etot * 8B  (<= N*64*4B)
    const int nsb  = (Etot + SORT_EPB - 1) / SORT_EPB;
    const int nb   = (N + (1 << BUCKET_SHIFT) - 1) >> BUCKET_SHIFT;
    const int hlen = nb * nsb;
    int* hist      = (int*)B;                   // hlen
    int* hist_scan = hist + hlen;               // hlen

    const int nScanBlocks = (hlen + SCAN_CHUNK - 1) / SCAN_CHUNK;
    const int gNode64 = (N + 63) / 64;
    const int gGather = (N + 15) / 16;
    const int gMlp    = ((E + 1) / 2 * 8 + 255) / 256;

    // ---- Build CSR by dst (edge set identical for all 3 layers) ----
    sort_hist<<<nsb, 256, 0, stream>>>(ei, hist, E, Etot, nb, nsb);
    scan_partial<<<nScanBlocks, 256, 0, stream>>>(hist, bsums, hlen);
    scan_bsums<<<1, 256, 0, stream>>>(bsums, nScanBlocks);
    scan_final_g<<<nScanBlocks, 256, 0, stream>>>(hist, bsums, hist_scan, hlen);
    sort_scatter<<<nsb, 256, 0, stream>>>(ei, hist_scan, staged, E, Etot, nb, nsb);
    bucket_fill<<<nb, 256, 0, stream>>>(staged, hist_scan, row_ptr, cols, N, Etot, nb, nsb);

    // h0 = x @ W0 + b0  -> A (N x 32)   [staged dead from here on]
    gemm_kernel<128, 32, false, false><<<gNode64, 256, 0, stream>>>(
        x, W0, b0, A, nullptr, nullptr, nullptr, nullptr, N);

    // ---- GAT layer 1: in A(32) -> h B(64) -> out C ----
    gemm_kernel<32, 64, false, true><<<gNode64, 256, 0, stream>>>(
        A, W1, nullptr, B, as1, ad1, alpha_s, alpha_d, N);
    gat_gather<true><<<gGather, 256, 0, stream>>>(
        row_ptr, cols, B, alpha_s, alpha_d, b1, C, N);

    // ---- GAT layer 2: in C -> h B -> out A ----
    gemm_kernel<64, 64, false, true><<<gNode64, 256, 0, stream>>>(
        C, W2, nullptr, B, as2, ad2, alpha_s, alpha_d, N);
    gat_gather<true><<<gGather, 256, 0, stream>>>(
        row_ptr, cols, B, alpha_s, alpha_d, b2, A, N);

    // ---- GAT layer 3: in A -> h B -> out C (no relu) ----
    gemm_kernel<64, 64, false, true><<<gNode64, 256, 0, stream>>>(
        A, W3, nullptr, B, as3, ad3, alpha_s, alpha_d, N);
    gat_gather<false><<<gGather, 256, 0, stream>>>(
        row_ptr, cols, B, alpha_s, alpha_d, b3, C, N);

    // ---- Final MLP, factorized over nodes (fused dual GEMM) ----
    float* Psrc = A;
    float* Pdst = A + (size_t)N * 32;
    gemm_dual<<<gNode64, 256, 0, stream>>>(C, Wm1, bm1, Psrc, Pdst, N);

    edge_mlp<<<gMlp, 256, 0, stream>>>(ei, Psrc, Pdst, Wm2, bm2, out, E);
}